// Round 11
// baseline (499.928 us; speedup 1.0000x reference)
//
#include <hip/hip_runtime.h>

#define P_TOT 5456
#define NANCH 49104
#define KTOP 1000
#define CAND_CAP 2048

typedef unsigned long long u64;
typedef unsigned int u32;

// Blocked-transposed feature layout: float4 index = blk*1024 + c4*64 + pxin
// Block 86 of each feature buffer is all-zeros (border-tap target).
// Buffer rotation (race-free): every kernel's read-set and write-set are disjoint.

__device__ __forceinline__ void level_of(int p, int& l, int& off, int& W, int& sh) {
  if (p < 4096)      { l = 0; off = 0;    W = 64; sh = 6; }
  else if (p < 5120) { l = 1; off = 4096; W = 32; sh = 5; }
  else if (p < 5376) { l = 2; off = 5120; W = 16; sh = 4; }
  else if (p < 5440) { l = 3; off = 5376; W = 8;  sh = 3; }
  else               { l = 4; off = 5440; W = 4;  sh = 2; }
}

// ---------------- prep: weight repack + all zero-inits ----------------
__global__ void k_prep(const float* __restrict__ clsw, const float* __restrict__ regw,
                       const float* __restrict__ clsow, const float* __restrict__ regow,
                       float* __restrict__ RWc, float* __restrict__ RWr,
                       float* __restrict__ RWco, float* __restrict__ RWro,
                       u32* __restrict__ zhist, float* __restrict__ A, float* __restrict__ Bb,
                       float* __restrict__ Cb, float* __restrict__ Db) {
  int idx = blockIdx.x * 256 + threadIdx.x;
  if (idx < 656640) {
    const float* src; float* dst; int OC, local;
    if (idx < 110592)      { src = clsw;  dst = RWc;  OC = 64;  local = idx; }
    else if (idx < 221184) { src = regw;  dst = RWr;  OC = 64;  local = idx - 110592; }
    else if (idx < 635904) { src = clsow; dst = RWco; OC = 720; local = idx - 221184; }
    else                   { src = regow; dst = RWro; OC = 36;  local = idx - 635904; }
    int per = OC * 576;
    int layer = local / per;
    int rem = local - layer * per;
    int oc = rem / 576;
    int r2 = rem - oc * 576;
    int c = r2 / 9;
    int k = r2 - c * 9;
    dst[layer * per + (k * OC + oc) * 64 + c] = src[local];
    return;
  }
  int z = idx - 656640;
  if (z < 131136) { zhist[z] = 0; return; }      // hist1 + hist2 + ctrl
  z -= 131136;
  if (z < 16384) {
    float* buf = (z < 4096) ? A : (z < 8192) ? Bb : (z < 12288) ? Cb : Db;
    buf[86 * 4096 + (z & 4095)] = 0.f;
    return;
  }
  z -= 16384;
  if (z < 1024) RWro[20736 + z] = 0.f;           // RWro pad (OOB-read safety)
}

// ---------------- fused FPN input convs (c3, c4, c5 1x1 + p6) ----------------
__global__ void k_fpn_in(const float* __restrict__ c3, const float* __restrict__ w3, const float* __restrict__ b3,
                         const float* __restrict__ c4i, const float* __restrict__ w4, const float* __restrict__ b4,
                         const float* __restrict__ c5, const float* __restrict__ w5, const float* __restrict__ b5,
                         const float* __restrict__ w6, const float* __restrict__ b6,
                         float* __restrict__ F, float4* __restrict__ F4) {
  int bx = blockIdx.x;
  if (bx < 320) {        // 1x1 convs (c3: blocks 0..255, c4: 256..319)
    const float* x; const float* w; const float* b; int Cin, npix, off, c4o, p;
    if (bx < 256) { x = c3; w = w3; b = b3; Cin = 40; npix = 4096; off = 0;
                    c4o = bx >> 4; p = (bx & 15) * 256 + threadIdx.x; }
    else          { int lo = bx - 256; x = c4i; w = w4; b = b4; Cin = 80; npix = 1024; off = 4096;
                    c4o = lo >> 2; p = (lo & 3) * 256 + threadIdx.x; }
    int oc4 = c4o * 4;
    float acc[4] = {0.f,0.f,0.f,0.f};
    for (int c = 0; c < Cin; ++c) {
      float xv = x[c * npix + p];
#pragma unroll
      for (int o = 0; o < 4; ++o)
        acc[o] = fmaf(w[(oc4 + o) * Cin + c], xv, acc[o]);
    }
    int px = off + p;
    float4 r;
    r.x = acc[0] + b[oc4 + 0]; r.y = acc[1] + b[oc4 + 1];
    r.z = acc[2] + b[oc4 + 2]; r.w = acc[3] + b[oc4 + 3];
    F4[((px >> 6) << 10) + (c4o << 6) + (px & 63)] = r;
  } else if (bx < 384) { // c5 1x1: one oc per block, 256 px
    int oc = bx - 320;
    int p = threadIdx.x;
    float acc = 0.f;
    for (int c = 0; c < 192; ++c)
      acc = fmaf(w5[oc * 192 + c], c5[c * 256 + p], acc);
    int px = 5120 + p;
    F[((px >> 6) << 12) + ((oc >> 2) << 8) + ((px & 63) << 2) + (oc & 3)] = acc + b5[oc];
  } else {               // p6 conv 3x3 s2: one oc per block
    int oc = bx - 384;
    int tid = threadIdx.x;
    int cg = tid >> 6, pix = tid & 63;
    int oy = pix >> 3, ox = pix & 7;
    float acc = 0.f;
    int c0 = cg * 48;
    for (int c = c0; c < c0 + 48; ++c) {
      const float* xc = c5 + c * 256;
      const float* wc = w6 + (oc * 192 + c) * 9;
#pragma unroll
      for (int ky = 0; ky < 3; ++ky) {
        int iy = oy * 2 + ky - 1;
        if ((unsigned)iy >= 16u) continue;
#pragma unroll
        for (int kx = 0; kx < 3; ++kx) {
          int ix = ox * 2 + kx - 1;
          if ((unsigned)ix >= 16u) continue;
          acc = fmaf(wc[ky * 3 + kx], xc[iy * 16 + ix], acc);
        }
      }
    }
    __shared__ float red[4][64];
    red[cg][pix] = acc;
    __syncthreads();
    if (cg == 0) {
      float s = red[0][pix] + red[1][pix] + red[2][pix] + red[3][pix] + b6[oc];
      F[(84 << 12) + ((oc >> 2) << 8) + (pix << 2) + (oc & 3)] = s;
    }
  }
}

__global__ void k_conv_p7(const float* __restrict__ w, const float* __restrict__ b,
                          float* __restrict__ F) {
  int oc = blockIdx.x;
  int t = threadIdx.x;
  int cg = t >> 4, pix = t & 15;
  int oy = pix >> 2, ox = pix & 3;
  float acc = 0.f;
  int c0 = cg * 16;
  for (int c = c0; c < c0 + 16; ++c) {
#pragma unroll
    for (int ky = 0; ky < 3; ++ky) {
      int iy = oy * 2 + ky - 1;
      if ((unsigned)iy >= 8u) continue;
#pragma unroll
      for (int kx = 0; kx < 3; ++kx) {
        int ix = ox * 2 + kx - 1;
        if ((unsigned)ix >= 8u) continue;
        float xv = fmaxf(F[(84 << 12) + ((c >> 2) << 8) + ((iy * 8 + ix) << 2) + (c & 3)], 0.f);
        acc = fmaf(w[(oc * 64 + c) * 9 + ky * 3 + kx], xv, acc);
      }
    }
  }
  acc += __shfl_down(acc, 32);
  acc += __shfl_down(acc, 16);
  if (cg == 0)
    F[(85 << 12) + ((oc >> 2) << 8) + (pix << 2) + (oc & 3)] = acc + b[oc];
}

// ---------------- BiFPN td / out (K-split x4: one group, 4 K-quarters per block) ----------------
__global__ __launch_bounds__(256) void k_td_t(const float4* __restrict__ F4, float4* __restrict__ TD4,
                     const float* __restrict__ tw, const float* __restrict__ tb,
                     const float* __restrict__ tg, const float* __restrict__ tbt,
                     const float* __restrict__ tm, const float* __restrict__ tv,
                     const float* __restrict__ w1raw, int blk) {
  int bx = blockIdx.x, S = bx * 64;
  int l, off, W, sh; level_of(S, l, off, W, sh);
  int tid = threadIdx.x;
  if (l == 4) {                      // p7td = p7x copy (16 px x 16 c4)
    if (blockIdx.y == 0) {
      int pxrel = tid >> 4, c4 = tid & 15;
      TD4[(85 << 10) + (c4 << 6) + pxrel] = F4[(85 << 10) + (c4 << 6) + pxrel];
    }
    return;
  }
  __shared__ float part[3][8][64];
  float wav = fmaxf(w1raw[blk * 2 + 0], 0.f);
  float wbv = fmaxf(w1raw[blk * 2 + 1], 0.f);
  float s = wav + wbv + 1e-4f;
  wav /= s; wbv /= s;
  int lane = tid & 63;
  int kh = __builtin_amdgcn_readfirstlane(tid >> 6);   // K-quarter 0..3
  int g = blockIdx.y;                // group 0..7
  int ocb = g * 8;
  int px = S + lane;
  int loc = px - off, yy = loc >> sh, xx = loc & (W - 1);
  int Wu = W >> 1;
  int pup = off + W * W + (yy >> 1) * Wu + (xx >> 1);
  int c4base = kh * 4;
  int fup = ((pup >> 6) << 10) + (pup & 63) + (c4base << 6);
  int fself = (bx << 10) + lane + (c4base << 6);
  float acc[8] = {};
  const float4* wt4 = (const float4*)tw + (size_t)((blk * 5 + l) * 64) * 16 + c4base;
#pragma unroll
  for (int c4 = 0; c4 < 4; ++c4) {
    float4 a = F4[fself + (c4 << 6)];
    float4 b = F4[fup + (c4 << 6)];
    float4 fin;
    fin.x = wav * a.x + wbv * b.x; fin.y = wav * a.y + wbv * b.y;
    fin.z = wav * a.z + wbv * b.z; fin.w = wav * a.w + wbv * b.w;
#pragma unroll
    for (int o = 0; o < 8; ++o) {
      float4 wv = wt4[(ocb + o) * 16 + c4];
      acc[o] = fmaf(fin.x, wv.x, fmaf(fin.y, wv.y, fmaf(fin.z, wv.z, fmaf(fin.w, wv.w, acc[o]))));
    }
  }
  if (kh) {
#pragma unroll
    for (int o = 0; o < 8; ++o) part[kh - 1][o][lane] = acc[o];
  }
  __syncthreads();
  if (kh) return;
#pragma unroll
  for (int o = 0; o < 8; ++o)
    acc[o] += part[0][o][lane] + part[1][o][lane] + part[2][o][lane];
  int idxbase = (blk * 5 + l) * 64 + ocb;
#pragma unroll
  for (int q = 0; q < 2; ++q) {
    float r[4];
#pragma unroll
    for (int j = 0; j < 4; ++j) {
      int o = q * 4 + j, idx = idxbase + o;
      float xv = acc[o] + tb[idx];
      float inv = 1.0f / sqrtf(tv[idx] + 4e-5f);
      r[j] = (xv - tm[idx]) * (tg[idx] * inv) + tbt[idx];
    }
    float4 rq; rq.x = r[0]; rq.y = r[1]; rq.z = r[2]; rq.w = r[3];
    TD4[(bx << 10) + (((ocb >> 2) + q) << 6) + lane] = rq;
  }
}

__global__ __launch_bounds__(256) void k_out_t(const float4* __restrict__ F4, const float4* __restrict__ TD4,
                      float4* __restrict__ OUT4,
                      const float* __restrict__ ow, const float* __restrict__ ob,
                      const float* __restrict__ og, const float* __restrict__ obt,
                      const float* __restrict__ om, const float* __restrict__ ov,
                      const float* __restrict__ w2raw, int blk) {
  int bx = blockIdx.x, S = bx * 64;
  int l, off, W, sh; level_of(S, l, off, W, sh);
  int tid = threadIdx.x;
  if (l == 0) {                      // new feats level3 = p3td copy
    if (blockIdx.y == 0)
      for (int j = tid; j < 1024; j += 256)
        OUT4[(bx << 10) + j] = TD4[(bx << 10) + j];
    return;
  }
  __shared__ float part[3][8][64];
  float wav = fmaxf(w2raw[blk * 3 + 0], 0.f);
  float wbv = fmaxf(w2raw[blk * 3 + 1], 0.f);
  float wcv = fmaxf(w2raw[blk * 3 + 2], 0.f);
  float s = wav + wbv + wcv + 1e-4f;
  wav /= s; wbv /= s; wcv /= s;
  int lane = tid & 63;
  int kh = __builtin_amdgcn_readfirstlane(tid >> 6);   // K-quarter 0..3
  int g = blockIdx.y;                // group 0..7
  int ocb = g * 8;
  int px = S + lane;
  bool pxok = px < P_TOT;
  int loc = px - off, yy = loc >> sh, xx = loc & (W - 1);
  int Wd = W << 1;
  int offd = off - Wd * Wd;
  int pdn = offd + (2 * yy) * Wd + 2 * xx;
  int c4base = kh * 4;
  int fself = (bx << 10) + lane + (c4base << 6);
  int fdn = (pxok ? (((pdn >> 6) << 10) + (pdn & 63)) : ((bx << 10) + lane)) + (c4base << 6);
  float acc[8] = {};
  const float4* wt4 = (const float4*)ow + (size_t)((blk * 5 + l) * 64) * 16 + c4base;
#pragma unroll
  for (int c4 = 0; c4 < 4; ++c4) {
    float4 a = F4[fself + (c4 << 6)];
    float4 b = TD4[fself + (c4 << 6)];
    float4 c = TD4[fdn + (c4 << 6)];
    float4 fin;
    fin.x = wav * a.x + wbv * b.x + wcv * c.x;
    fin.y = wav * a.y + wbv * b.y + wcv * c.y;
    fin.z = wav * a.z + wbv * b.z + wcv * c.z;
    fin.w = wav * a.w + wbv * b.w + wcv * c.w;
#pragma unroll
    for (int o = 0; o < 8; ++o) {
      float4 wv = wt4[(ocb + o) * 16 + c4];
      acc[o] = fmaf(fin.x, wv.x, fmaf(fin.y, wv.y, fmaf(fin.z, wv.z, fmaf(fin.w, wv.w, acc[o]))));
    }
  }
  if (kh) {
#pragma unroll
    for (int o = 0; o < 8; ++o) part[kh - 1][o][lane] = acc[o];
  }
  __syncthreads();
  if (kh || !pxok) return;
#pragma unroll
  for (int o = 0; o < 8; ++o)
    acc[o] += part[0][o][lane] + part[1][o][lane] + part[2][o][lane];
  int idxbase = (blk * 5 + l) * 64 + ocb;
#pragma unroll
  for (int q = 0; q < 2; ++q) {
    float r[4];
#pragma unroll
    for (int j = 0; j < 4; ++j) {
      int o = q * 4 + j, idx = idxbase + o;
      float xv = acc[o] + ob[idx];
      float inv = 1.0f / sqrtf(ov[idx] + 4e-5f);
      r[j] = (xv - om[idx]) * (og[idx] * inv) + obt[idx];
    }
    float4 rq; rq.x = r[0]; rq.y = r[1]; rq.z = r[2]; rq.w = r[3];
    OUT4[(bx << 10) + (((ocb >> 2) + q) << 6) + lane] = rq;
  }
}

// ---------------- tap index helper (zero-block for borders) ----------------
__device__ __forceinline__ void tap_idx(int px, int off, int W, int sh, int fidx[9]) {
  int loc = px - off, y = loc >> sh, x = loc & (W - 1);
  int zb = (86 << 10) + (px & 63);
#pragma unroll
  for (int ky = 0; ky < 3; ++ky)
#pragma unroll
    for (int kx = 0; kx < 3; ++kx) {
      int iy = y + ky - 1, ix = x + kx - 1;
      bool v = ((unsigned)iy < (unsigned)W) && ((unsigned)ix < (unsigned)W);
      int pp = px + (ky - 1) * W + (kx - 1);
      fidx[ky * 3 + kx] = v ? (((pp >> 6) << 10) + (pp & 63)) : zb;
    }
}

// merged reg+cls 64->64 layer, K-split x4: block = one group x 4 K-quarters
// g 0-7 -> reg chain, 8-15 -> cls chain
__global__ __launch_bounds__(256) void k_conv3m(const float4* __restrict__ Fr, const float4* __restrict__ Fc,
                        float4* __restrict__ Or, float4* __restrict__ Oc,
                        const float* __restrict__ RWr, const float* __restrict__ RWc,
                        const float* __restrict__ br, const float* __restrict__ bc) {
  __shared__ float part[3][8][64];
  int S = blockIdx.x * 64;
  int l, off, W, sh; level_of(S, l, off, W, sh);
  int lane = threadIdx.x & 63;
  int kh = __builtin_amdgcn_readfirstlane(threadIdx.x >> 6);  // K-quarter 0..3
  int g = blockIdx.y;   // 0..15
  const float4* X; float4* O; const float* RW; const float* bias; int ocb;
  if (g < 8) { X = Fr; O = Or; RW = RWr; bias = br; ocb = g * 8; }
  else       { X = Fc; O = Oc; RW = RWc; bias = bc; ocb = (g - 8) * 8; }
  int px = S + lane;
  int fidx[9];
  tap_idx(px, off, W, sh, fidx);
  float acc[8];
#pragma unroll
  for (int o = 0; o < 8; ++o) acc[o] = 0.f;
  int c4base = kh * 4;
  const float4* W4 = (const float4*)RW + c4base;
#pragma unroll
  for (int t = 0; t < 9; ++t) {
    const float4* wb = W4 + (size_t)(t * 64 + ocb) * 16;
    int fi = fidx[t] + (c4base << 6);
#pragma unroll
    for (int c4 = 0; c4 < 4; ++c4) {
      float4 xv = X[fi + (c4 << 6)];
#pragma unroll
      for (int o = 0; o < 8; ++o) {
        float4 wv = wb[o * 16 + c4];
        acc[o] = fmaf(xv.x, wv.x, fmaf(xv.y, wv.y, fmaf(xv.z, wv.z, fmaf(xv.w, wv.w, acc[o]))));
      }
    }
  }
  if (kh) {
#pragma unroll
    for (int o = 0; o < 8; ++o) part[kh - 1][o][lane] = acc[o];
  }
  __syncthreads();
  if (kh || px >= P_TOT) return;
#pragma unroll
  for (int o = 0; o < 8; ++o)
    acc[o] += part[0][o][lane] + part[1][o][lane] + part[2][o][lane];
#pragma unroll
  for (int q = 0; q < 2; ++q) {
    float4 r;
    r.x = fmaxf(acc[q*4+0] + bias[ocb+q*4+0], 0.f);
    r.y = fmaxf(acc[q*4+1] + bias[ocb+q*4+1], 0.f);
    r.z = fmaxf(acc[q*4+2] + bias[ocb+q*4+2], 0.f);
    r.w = fmaxf(acc[q*4+3] + bias[ocb+q*4+3], 0.f);
    O[(blockIdx.x << 10) + (((ocb >> 2) + q) << 6) + lane] = r;
  }
}

// cls-out + reg-out conv, fused; pair-units of 16 oc; K-split halves; 1 px/lane.
// Pair p: 0..44 cls (oc 16p..16p+15, exactly one anchor each: 80%16==0),
//         45..47 reg (oc 16(p-45)..+15, valid <36).
// cls partials: pamax[p*5504+px], 5 partials per anchor. key = mono32(logit)<<32 | (127-cls).
__global__ __launch_bounds__(256) void k_conv3c(const float4* __restrict__ Fc, const float4* __restrict__ Fr,
                        const float* __restrict__ RWc, const float* __restrict__ bc,
                        const float* __restrict__ RWr, const float* __restrict__ br,
                        u64* __restrict__ pamax, float* __restrict__ REGb) {
  __shared__ float part[2][16][64];
  int lane = threadIdx.x & 63;
  int wid = __builtin_amdgcn_readfirstlane(threadIdx.x >> 6);
  int gp = wid >> 1, kh = wid & 1;
  int p = blockIdx.y * 2 + gp;          // pair-unit 0..47
  bool is_cls = p < 45;
  int ocb, OCw; const float4* W4; const float4* F4;
  if (is_cls) { ocb = p * 16; OCw = 720; W4 = (const float4*)RWc; F4 = Fc; }
  else        { ocb = (p - 45) * 16; OCw = 36; W4 = (const float4*)RWr; F4 = Fr; }
  int S = blockIdx.x * 64;
  int px = S + lane;
  bool pxok = px < P_TOT;
  int l, off, W, sh;
  level_of(px, l, off, W, sh);
  int f1[9];
  tap_idx(px, off, W, sh, f1);
  float a1[16];
#pragma unroll
  for (int o = 0; o < 16; ++o) a1[o] = 0.f;
  int c4base = kh * 8;
  const float4* W4b = W4 + c4base;
#pragma unroll
  for (int t = 0; t < 9; ++t) {
    const float4* wb = W4b + (size_t)(t * OCw + ocb) * 16;
    int fi = f1[t] + (c4base << 6);
#pragma unroll 4
    for (int c4 = 0; c4 < 8; ++c4) {
      float4 x1 = F4[fi + (c4 << 6)];
#pragma unroll
      for (int o = 0; o < 16; ++o) {
        float4 wv = wb[o * 16 + c4];
        a1[o] = fmaf(x1.x, wv.x, fmaf(x1.y, wv.y, fmaf(x1.z, wv.z, fmaf(x1.w, wv.w, a1[o]))));
      }
    }
  }
  if (kh) {
#pragma unroll
    for (int o = 0; o < 16; ++o) part[gp][o][lane] = a1[o];
  }
  __syncthreads();
  if (kh) return;
#pragma unroll
  for (int o = 0; o < 16; ++o) a1[o] += part[gp][o][lane];
  if (!pxok) return;
  if (is_cls) {
    int cls0 = (p % 5) * 16;
    u64 k1 = 0ULL;
#pragma unroll
    for (int o = 0; o < 16; ++o) {
      float v1 = a1[o] + bc[ocb + o];
      u32 b1 = __float_as_uint(v1);
      b1 = (b1 & 0x80000000u) ? ~b1 : (b1 | 0x80000000u);
      u64 key1 = ((u64)b1 << 32) | (u32)(127 - (cls0 + o));
      k1 = k1 > key1 ? k1 : key1;
    }
    pamax[p * 5504 + px] = k1;
  } else {
    int nv = min(16, 36 - ocb);      // 16, 16, 4
    for (int o = 0; o < nv; ++o) {
      int oc = ocb + o;
      float v1 = a1[o] + br[oc];
      REGb[((size_t)(px >> 6) * 9 + (oc >> 2)) * 256 + (px & 63) * 4 + (oc & 3)] = v1;
    }
  }
}

// ---------------- decode boxes + score/label from pamax ----------------
__global__ void k_decode_score(const float4* __restrict__ REG4, const u64* __restrict__ pamax,
                               float* __restrict__ score, int* __restrict__ label,
                               float* __restrict__ boxes, u32* __restrict__ ukey,
                               u32* __restrict__ hist1) {
  int aid = blockIdx.x * 256 + threadIdx.x;
  if (aid >= NANCH) return;
  int p = aid / 9;
  int a = aid - p * 9;
  int l, off, W, sh; level_of(p, l, off, W, sh);
  int loc = p - off, y = loc >> sh, x = loc & (W - 1);
  int s_idx = a % 3, r_idx = a / 3;
  double scale = (s_idx == 0) ? 1.0 : ((s_idx == 1) ? 1.2599210498948732 : 1.5874010519681994);
  double ratio = (r_idx == 0) ? 0.5 : ((r_idx == 1) ? 1.0 : 2.0);
  double strided = (double)(8 << l);
  double based = (double)(32 << l);
  double w0 = based * scale;
  double wA = sqrt(w0 * w0 / ratio);
  double hA = wA * ratio;
  double cxd = (x + 0.5) * strided;
  double cyd = (y + 0.5) * strided;
  float ax1 = (float)(cxd - wA / 2.0);
  float ay1 = (float)(cyd - hA / 2.0);
  float ax2 = (float)(cxd + wA / 2.0);
  float ay2 = (float)(cyd + hA / 2.0);
  float wa = ax2 - ax1, ha = ay2 - ay1;
  float cxa = ax1 + 0.5f * wa, cya = ay1 + 0.5f * ha;
  int blk = p >> 6, pxin = p & 63;
  float4 rq = REG4[blk * 576 + (a << 6) + pxin];
  float ncx = cxa + (rq.x * 0.1f) * wa;
  float ncy = cya + (rq.y * 0.1f) * ha;
  float nw = expf(rq.z * 0.2f) * wa;
  float nh = expf(rq.w * 0.2f) * ha;
  float bx1 = fmaxf(ncx - 0.5f * nw, 0.f);
  float by1 = fmaxf(ncy - 0.5f * nh, 0.f);
  float bx2 = fminf(ncx + 0.5f * nw, 512.f);
  float by2 = fminf(ncy + 0.5f * nh, 512.f);
  boxes[aid * 4 + 0] = bx1; boxes[aid * 4 + 1] = by1;
  boxes[aid * 4 + 2] = bx2; boxes[aid * 4 + 3] = by2;
  u64 key = 0ULL;
  const u64* pa = pamax + (size_t)(a * 5) * 5504 + p;
#pragma unroll
  for (int gi = 0; gi < 5; ++gi) {
    u64 k = pa[gi * 5504];
    key = key > k ? key : k;
  }
  u32 b = (u32)(key >> 32);
  b = (b & 0x80000000u) ? (b & 0x7FFFFFFFu) : ~b;
  float best = __uint_as_float(b);
  int bl = 127 - (int)(key & 0xFFFFFFFFu);
  float sc = 1.f / (1.f + expf(-best));
  score[aid] = sc; label[aid] = bl;
  u32 u = 0u;
  if (sc > 0.05f) u = __float_as_uint(sc) | 0x80000000u;
  ukey[aid] = u;
  if (u) atomicAdd(&hist1[u >> 16], 1u);
}

// ---------------- radix-select scans ----------------
__global__ __launch_bounds__(1024) void k_scanA(const u32* __restrict__ hist, u32* __restrict__ ctrl) {
  __shared__ u32 cs[1024];
  u32 s = 0;
  int base = threadIdx.x * 64;
  for (int b = 0; b < 64; ++b) s += hist[base + b];
  cs[threadIdx.x] = s;
  __syncthreads();
  if (threadIdx.x == 0) {
    u32 cum = 0; int cc = -1;
    for (int tt = 1023; tt >= 0; --tt) {
      if (cum + cs[tt] >= (u32)KTOP) { cc = tt; break; }
      cum += cs[tt];
    }
    if (cc < 0) {
      ctrl[0] = 0x20000u; ctrl[1] = cum; ctrl[2] = 1u;
    } else {
      u32 c2 = cum; int B1 = cc * 64; u32 hB1 = 0;
      for (int b = cc * 64 + 63; b >= cc * 64; --b) {
        u32 h = hist[b];
        if (c2 + h >= (u32)KTOP) { B1 = b; hB1 = h; break; }
        c2 += h;
      }
      ctrl[0] = (u32)B1; ctrl[1] = c2;
      if (c2 + hB1 <= (u32)CAND_CAP) {   // whole bucket fits: skip pass 2
        ctrl[2] = (u32)B1 << 16;
        ctrl[5] = 1u;
      }
    }
  }
}

__global__ void k_histB(const u32* __restrict__ ukey, u32* __restrict__ hist2,
                        const u32* __restrict__ ctrl) {
  if (ctrl[5]) return;
  int aid = blockIdx.x * 256 + threadIdx.x;
  if (aid >= NANCH) return;
  u32 u = ukey[aid];
  if (u && (u >> 16) == ctrl[0]) atomicAdd(&hist2[u & 0xFFFFu], 1u);
}

__global__ __launch_bounds__(1024) void k_scanB(const u32* __restrict__ hist, u32* __restrict__ ctrl) {
  if (ctrl[0] > 0xFFFFu || ctrl[5]) return;
  __shared__ u32 cs[1024];
  u32 s = 0;
  int base = threadIdx.x * 64;
  for (int b = 0; b < 64; ++b) s += hist[base + b];
  cs[threadIdx.x] = s;
  __syncthreads();
  if (threadIdx.x == 0) {
    u32 CA = ctrl[1];
    u32 cum = CA; int cc = -1;
    for (int tt = 1023; tt >= 0; --tt) {
      if (cum + cs[tt] >= (u32)KTOP) { cc = tt; break; }
      cum += cs[tt];
    }
    u32 B2 = 0;
    if (cc >= 0) {
      for (int b = cc * 64 + 63; b >= cc * 64; --b) {
        u32 h = hist[b];
        if (cum + h >= (u32)KTOP) { B2 = (u32)b; break; }
        cum += h;
      }
    }
    ctrl[2] = (ctrl[0] << 16) | B2;
  }
}

__global__ void k_compact(const u32* __restrict__ ukey, u64* __restrict__ cand,
                          u32* __restrict__ ctrl) {
  int aid = blockIdx.x * 256 + threadIdx.x;
  if (aid >= NANCH) return;
  u32 u = ukey[aid];
  u32 T = ctrl[2];
  if (u >= T && u != 0) {
    u32 pos = atomicAdd(&ctrl[3], 1u);
    if (pos < (u32)CAND_CAP)
      cand[pos] = (((u64)u) << 32) | (u32)(~(u32)aid);
  }
}

// ---------------- bitonic sort + select top-1000 ----------------
__global__ __launch_bounds__(1024) void k_sortsel(const u64* __restrict__ cand, u32* __restrict__ ctrl,
                                                  const float* __restrict__ score, const int* __restrict__ label,
                                                  const float* __restrict__ boxes,
                                                  float* __restrict__ tops, int* __restrict__ topl,
                                                  float* __restrict__ topb) {
  __shared__ u64 key[CAND_CAP];
  int C = min((int)ctrl[3], CAND_CAP);
  for (int i = threadIdx.x; i < CAND_CAP; i += 1024) key[i] = (i < C) ? cand[i] : 0ULL;
  __syncthreads();
  for (int k = 2; k <= CAND_CAP; k <<= 1) {
    for (int j = k >> 1; j > 0; j >>= 1) {
      for (int t = threadIdx.x; t < CAND_CAP / 2; t += 1024) {
        int i1 = ((t & ~(j - 1)) << 1) | (t & (j - 1));
        int i2 = i1 + j;
        bool up = (i1 & k) != 0;
        u64 a = key[i1], b = key[i2];
        bool sw = up ? (a > b) : (a < b);
        if (sw) { key[i1] = b; key[i2] = a; }
      }
      __syncthreads();
    }
  }
  if (threadIdx.x < KTOP) {
    int r = threadIdx.x;
    u64 kk = key[r];
    u32 u = (u32)(kk >> 32);
    if (u != 0) {
      int aid = (int)(~((u32)kk));
      float sv = __uint_as_float(u & 0x7FFFFFFFu);
      tops[r] = sv; topl[r] = label[aid];
      topb[r * 4 + 0] = boxes[aid * 4 + 0];
      topb[r * 4 + 1] = boxes[aid * 4 + 1];
      topb[r * 4 + 2] = boxes[aid * 4 + 2];
      topb[r * 4 + 3] = boxes[aid * 4 + 3];
    } else {
      tops[r] = -1.f; topl[r] = -1;
      topb[r * 4 + 0] = 0.f; topb[r * 4 + 1] = 0.f;
      topb[r * 4 + 2] = 0.f; topb[r * 4 + 3] = 0.f;
    }
  }
  if (threadIdx.x == 0) ctrl[4] = (u32)min(C, KTOP);
}

// ---------------- NMS ----------------
__global__ void k_iou(const float* __restrict__ topb, const u32* __restrict__ ctrl,
                      u64* __restrict__ mask) {
  int wid = threadIdx.x >> 6, lane = threadIdx.x & 63;
  int i = blockIdx.x * 4 + wid;
  int V = (int)ctrl[4];
  if (i >= V) return;
  float x1i = topb[i * 4], y1i = topb[i * 4 + 1], x2i = topb[i * 4 + 2], y2i = topb[i * 4 + 3];
  float ai = fmaxf(x2i - x1i, 0.f) * fmaxf(y2i - y1i, 0.f);
  for (int w = 0; w < 16; ++w) {
    int j = w * 64 + lane;
    bool bit = false;
    if (j < KTOP && j > i) {
      float x1j = topb[j * 4], y1j = topb[j * 4 + 1], x2j = topb[j * 4 + 2], y2j = topb[j * 4 + 3];
      float aj = fmaxf(x2j - x1j, 0.f) * fmaxf(y2j - y1j, 0.f);
      float iw = fmaxf(fminf(x2i, x2j) - fmaxf(x1i, x1j), 0.f);
      float ih = fmaxf(fminf(y2i, y2j) - fmaxf(y1i, y1j), 0.f);
      float inter = iw * ih;
      float iou = inter / (ai + aj - inter + 1e-8f);
      bit = iou > 0.5f;
    }
    u64 m = __ballot(bit);
    if (lane == 0) mask[i * 16 + w] = m;
  }
}

// NMS scan (wave 0) + final output (all 256 threads), fused
__global__ __launch_bounds__(256) void k_nmsfinal(const u64* __restrict__ mask,
                                                  const float* __restrict__ tops,
                                                  const int* __restrict__ topl,
                                                  const float* __restrict__ topb,
                                                  float* __restrict__ out) {
  __shared__ char kf[KTOP];
  int tid = threadIdx.x;
  if (tid < 64) {
    const int la = tid;
    const int rg = la >> 4;
    const int wg = la & 15;
    u64 remw = 0ULL;

#define LOADB(b, upd, intra, vsc) do {                                   \
    int rb = (b) * 64;                                                   \
    _Pragma("unroll")                                                    \
    for (int k = 0; k < 16; ++k)                                         \
      upd[k] = mask[(u32)(rb + rg + 4 * k) * 16u + (u32)wg];             \
    intra = mask[(u32)(rb + la) * 16u + (u32)(b)];                       \
    vsc = tops[rb + la];                                                 \
  } while (0)

#define PROC(b, upd, intra, vsc) do {                                    \
    u64 validmask = __ballot((vsc) > 0.05f);                             \
    u32 ilo = (u32)(intra);                                              \
    u32 ihi = (u32)((intra) >> 32);                                      \
    u64 supmask = ((u64)__builtin_amdgcn_readlane((int)(remw >> 32), (b)) << 32) | \
                  (u32)__builtin_amdgcn_readlane((int)(u32)remw, (b));   \
    u64 keptmask = 0ULL;                                                 \
    for (int i = 0; i < 64; ++i) {                                       \
      u32 rlo = (u32)__builtin_amdgcn_readlane((int)ilo, i);             \
      u32 rhi = (u32)__builtin_amdgcn_readlane((int)ihi, i);             \
      u64 take = (u64)0 - (((validmask >> i) & 1ULL) & (~(supmask >> i) & 1ULL)); \
      keptmask |= (1ULL << i) & take;                                    \
      supmask |= (((u64)rhi << 32) | rlo) & take;                       \
    }                                                                    \
    u64 kk = keptmask >> rg;                                             \
    u64 acc = 0ULL;                                                      \
    _Pragma("unroll")                                                    \
    for (int k = 0; k < 16; ++k)                                         \
      if ((kk >> (4 * k)) & 1ULL) acc |= upd[k];                         \
    acc |= __shfl_xor(acc, 16);                                          \
    acc |= __shfl_xor(acc, 32);                                          \
    remw |= acc;                                                         \
    int j = (b) * 64 + la;                                               \
    if (j < KTOP) kf[j] = (char)((keptmask >> la) & 1ULL);               \
  } while (0)

    u64 updA[16], updB[16];
    u64 intraA, intraB;
    float vscA, vscB;
    LOADB(0, updA, intraA, vscA);
    for (int bb = 0; bb < 16; bb += 2) {
      if (bb + 1 < 16) LOADB(bb + 1, updB, intraB, vscB);
      PROC(bb, updA, intraA, vscA);
      if (bb + 2 < 16) LOADB(bb + 2, updA, intraA, vscA);
      if (bb + 1 < 16) PROC(bb + 1, updB, intraB, vscB);
    }
#undef LOADB
#undef PROC
  }
  __syncthreads();
  for (int r = tid; r < KTOP; r += 256) {
    int k = kf[r];
    out[r] = k ? tops[r] : 0.f;
    out[KTOP + r] = k ? (float)topl[r] : -1.f;
    out[2 * KTOP + r * 4 + 0] = k ? topb[r * 4 + 0] : 0.f;
    out[2 * KTOP + r * 4 + 1] = k ? topb[r * 4 + 1] : 0.f;
    out[2 * KTOP + r * 4 + 2] = k ? topb[r * 4 + 2] : 0.f;
    out[2 * KTOP + r * 4 + 3] = k ? topb[r * 4 + 3] : 0.f;
  }
}

extern "C" void kernel_launch(void* const* d_in, const int* in_sizes, int n_in,
                              void* d_out, int out_size, void* d_ws, size_t ws_size,
                              hipStream_t stream) {
  const float* c3    = (const float*)d_in[0];
  const float* c4i   = (const float*)d_in[1];
  const float* c5    = (const float*)d_in[2];
  const float* w3    = (const float*)d_in[3];  const float* b3 = (const float*)d_in[4];
  const float* w4    = (const float*)d_in[5];  const float* b4 = (const float*)d_in[6];
  const float* w5    = (const float*)d_in[7];  const float* b5 = (const float*)d_in[8];
  const float* w6    = (const float*)d_in[9];  const float* b6 = (const float*)d_in[10];
  const float* w7    = (const float*)d_in[11]; const float* b7 = (const float*)d_in[12];
  const float* tdw   = (const float*)d_in[13]; const float* tdb  = (const float*)d_in[14];
  const float* tdg   = (const float*)d_in[15]; const float* tdbt = (const float*)d_in[16];
  const float* tdm   = (const float*)d_in[17]; const float* tdv  = (const float*)d_in[18];
  const float* ow    = (const float*)d_in[19]; const float* ob   = (const float*)d_in[20];
  const float* og    = (const float*)d_in[21]; const float* obt  = (const float*)d_in[22];
  const float* om    = (const float*)d_in[23]; const float* ov   = (const float*)d_in[24];
  const float* w1    = (const float*)d_in[25]; const float* w2   = (const float*)d_in[26];
  const float* clsw  = (const float*)d_in[27]; const float* clsb = (const float*)d_in[28];
  const float* clsow = (const float*)d_in[29]; const float* clsob= (const float*)d_in[30];
  const float* regw  = (const float*)d_in[31]; const float* regb = (const float*)d_in[32];
  const float* regow = (const float*)d_in[33]; const float* regob= (const float*)d_in[34];

  float* ws = (float*)d_ws;
  const size_t NF = 356352;                 // 87 blks * 4096 floats (blk 86 = zeros)
  float* A    = ws;
  float* Bb   = ws + NF;
  float* Cb   = ws + 2 * NF;
  float* Db   = ws + 3 * NF;
  float* RWc  = ws + 4 * NF;                // 110592
  float* RWco = RWc + 110592;               // 414720
  float* RWr  = RWco + 414720;              // 110592
  float* RWro = RWr + 110592;               // 20736 + 1024 pad
  float* REGb = RWro + 21760;               // 198144 (86*2304)
  u64*   pamax = (u64*)(REGb + 198144);     // 45*5504 u64 (alloc 90*5504)
  float* scoreb = (float*)(pamax + 495360); // 49104
  int*   labelb = (int*)(scoreb + 49104);   // 49104
  float* boxesb = (float*)(labelb + 49104); // 196416
  u32* hist1 = (u32*)(boxesb + 196416);     // 65536
  u32* hist2 = hist1 + 65536;               // 65536
  u32* ctrl  = hist2 + 65536;               // 64
  u64* cand  = (u64*)(ctrl + 64);           // 2048 u64
  float* tops = (float*)(cand + CAND_CAP);  // 1024
  int*   topl = (int*)(tops + 1024);        // 1024
  float* topb = (float*)(topl + 1024);      // 4096
  u64*   mask = (u64*)(topb + 4096);        // 16384 u64
  u32*   ukeyb = (u32*)(mask + 16384);      // 49104

  float4* A4 = (float4*)A; float4* B4 = (float4*)Bb;
  float4* C4 = (float4*)Cb; float4* D4 = (float4*)Db;
  float4* REG4 = (float4*)REGb;

  // prep: repack all head weights + zero hist/ctrl/zero-blocks/RWro-pad
  k_prep<<<dim3(3146), 256, 0, stream>>>(clsw, regw, clsow, regow, RWc, RWr, RWco, RWro,
                                         hist1, A, Bb, Cb, Db);

  // FPN inputs (batch 0 only) -> blocked layout, into A
  k_fpn_in<<<dim3(448), 256, 0, stream>>>(c3, w3, b3, c4i, w4, b4, c5, w5, b5, w6, b6, A, A4);
  k_conv_p7<<<dim3(64), 64, 0, stream>>>(w7, b7, A);

  // BiFPN x2 (read/write disjoint per kernel; K-split x4)
  k_td_t<<<dim3(86, 8), 256, 0, stream>>>(A4, B4, tdw, tdb, tdg, tdbt, tdm, tdv, w1, 0);
  k_out_t<<<dim3(86, 8), 256, 0, stream>>>(A4, B4, C4, ow, ob, og, obt, om, ov, w2, 0);
  k_td_t<<<dim3(86, 8), 256, 0, stream>>>(C4, B4, tdw, tdb, tdg, tdbt, tdm, tdv, w1, 1);
  k_out_t<<<dim3(86, 8), 256, 0, stream>>>(C4, B4, A4, ow, ob, og, obt, om, ov, w2, 1);

  // heads: merged reg+cls 64->64 layers (K-split x4), 4-buffer rotation
  k_conv3m<<<dim3(86, 16), 256, 0, stream>>>(A4, A4, C4, D4, RWr, RWc, regb, clsb);
  k_conv3m<<<dim3(86, 16), 256, 0, stream>>>(C4, D4, B4, A4, RWr + 36864, RWc + 36864, regb + 64, clsb + 64);
  k_conv3m<<<dim3(86, 16), 256, 0, stream>>>(B4, A4, C4, D4, RWr + 73728, RWc + 73728, regb + 128, clsb + 128);
  // reg final features in Cb, cls final features in Db; fused cls-out + reg-out (16 oc/wave)
  k_conv3c<<<dim3(86, 24), 256, 0, stream>>>(D4, C4, RWco, clsob, RWro, regob, pamax, REGb);

  // decode + score + top-k + NMS
  k_decode_score<<<dim3(192), 256, 0, stream>>>(REG4, pamax, scoreb, labelb, boxesb, ukeyb, hist1);
  k_scanA<<<dim3(1), 1024, 0, stream>>>(hist1, ctrl);
  k_histB<<<dim3(192), 256, 0, stream>>>(ukeyb, hist2, ctrl);
  k_scanB<<<dim3(1), 1024, 0, stream>>>(hist2, ctrl);
  k_compact<<<dim3(192), 256, 0, stream>>>(ukeyb, cand, ctrl);
  k_sortsel<<<dim3(1), 1024, 0, stream>>>(cand, ctrl, scoreb, labelb, boxesb, tops, topl, topb);
  k_iou<<<dim3(250), 256, 0, stream>>>(topb, ctrl, mask);
  k_nmsfinal<<<dim3(1), 256, 0, stream>>>(mask, tops, topl, topb, (float*)d_out);
}

// Round 12
// 421.258 us; speedup vs baseline: 1.1867x; 1.1867x over previous
//
#include <hip/hip_runtime.h>

#define P_TOT 5456
#define NANCH 49104
#define KTOP 1000
#define CAND_CAP 2048

typedef unsigned long long u64;
typedef unsigned int u32;

// Blocked-transposed feature layout: float4 index = blk*1024 + c4*64 + pxin
// Block 86 of each feature buffer is all-zeros (border-tap target).
// Buffer rotation (race-free): every kernel's read-set and write-set are disjoint.

__device__ __forceinline__ void level_of(int p, int& l, int& off, int& W, int& sh) {
  if (p < 4096)      { l = 0; off = 0;    W = 64; sh = 6; }
  else if (p < 5120) { l = 1; off = 4096; W = 32; sh = 5; }
  else if (p < 5376) { l = 2; off = 5120; W = 16; sh = 4; }
  else if (p < 5440) { l = 3; off = 5376; W = 8;  sh = 3; }
  else               { l = 4; off = 5440; W = 4;  sh = 2; }
}

// ---------------- prep: weight repack + all zero-inits ----------------
__global__ void k_prep(const float* __restrict__ clsw, const float* __restrict__ regw,
                       const float* __restrict__ clsow, const float* __restrict__ regow,
                       float* __restrict__ RWc, float* __restrict__ RWr,
                       float* __restrict__ RWco, float* __restrict__ RWro,
                       u32* __restrict__ zhist, float* __restrict__ A, float* __restrict__ Bb,
                       float* __restrict__ Cb, float* __restrict__ Db) {
  int idx = blockIdx.x * 256 + threadIdx.x;
  if (idx < 656640) {
    const float* src; float* dst; int OC, local;
    if (idx < 110592)      { src = clsw;  dst = RWc;  OC = 64;  local = idx; }
    else if (idx < 221184) { src = regw;  dst = RWr;  OC = 64;  local = idx - 110592; }
    else if (idx < 635904) { src = clsow; dst = RWco; OC = 720; local = idx - 221184; }
    else                   { src = regow; dst = RWro; OC = 36;  local = idx - 635904; }
    int per = OC * 576;
    int layer = local / per;
    int rem = local - layer * per;
    int oc = rem / 576;
    int r2 = rem - oc * 576;
    int c = r2 / 9;
    int k = r2 - c * 9;
    dst[layer * per + (k * OC + oc) * 64 + c] = src[local];
    return;
  }
  int z = idx - 656640;
  if (z < 131136) { zhist[z] = 0; return; }      // hist1 + hist2 + ctrl
  z -= 131136;
  if (z < 16384) {
    float* buf = (z < 4096) ? A : (z < 8192) ? Bb : (z < 12288) ? Cb : Db;
    buf[86 * 4096 + (z & 4095)] = 0.f;
    return;
  }
  z -= 16384;
  if (z < 1024) RWro[20736 + z] = 0.f;           // RWro pad (OOB-read safety)
}

// ---------------- fused FPN input convs (c3, c4, c5 1x1 + p6) ----------------
__global__ void k_fpn_in(const float* __restrict__ c3, const float* __restrict__ w3, const float* __restrict__ b3,
                         const float* __restrict__ c4i, const float* __restrict__ w4, const float* __restrict__ b4,
                         const float* __restrict__ c5, const float* __restrict__ w5, const float* __restrict__ b5,
                         const float* __restrict__ w6, const float* __restrict__ b6,
                         float* __restrict__ F, float4* __restrict__ F4) {
  int bx = blockIdx.x;
  if (bx < 320) {        // 1x1 convs (c3: blocks 0..255, c4: 256..319)
    const float* x; const float* w; const float* b; int Cin, npix, off, c4o, p;
    if (bx < 256) { x = c3; w = w3; b = b3; Cin = 40; npix = 4096; off = 0;
                    c4o = bx >> 4; p = (bx & 15) * 256 + threadIdx.x; }
    else          { int lo = bx - 256; x = c4i; w = w4; b = b4; Cin = 80; npix = 1024; off = 4096;
                    c4o = lo >> 2; p = (lo & 3) * 256 + threadIdx.x; }
    int oc4 = c4o * 4;
    float acc[4] = {0.f,0.f,0.f,0.f};
    for (int c = 0; c < Cin; ++c) {
      float xv = x[c * npix + p];
#pragma unroll
      for (int o = 0; o < 4; ++o)
        acc[o] = fmaf(w[(oc4 + o) * Cin + c], xv, acc[o]);
    }
    int px = off + p;
    float4 r;
    r.x = acc[0] + b[oc4 + 0]; r.y = acc[1] + b[oc4 + 1];
    r.z = acc[2] + b[oc4 + 2]; r.w = acc[3] + b[oc4 + 3];
    F4[((px >> 6) << 10) + (c4o << 6) + (px & 63)] = r;
  } else if (bx < 384) { // c5 1x1: one oc per block, 256 px
    int oc = bx - 320;
    int p = threadIdx.x;
    float acc = 0.f;
    for (int c = 0; c < 192; ++c)
      acc = fmaf(w5[oc * 192 + c], c5[c * 256 + p], acc);
    int px = 5120 + p;
    F[((px >> 6) << 12) + ((oc >> 2) << 8) + ((px & 63) << 2) + (oc & 3)] = acc + b5[oc];
  } else {               // p6 conv 3x3 s2: one oc per block
    int oc = bx - 384;
    int tid = threadIdx.x;
    int cg = tid >> 6, pix = tid & 63;
    int oy = pix >> 3, ox = pix & 7;
    float acc = 0.f;
    int c0 = cg * 48;
    for (int c = c0; c < c0 + 48; ++c) {
      const float* xc = c5 + c * 256;
      const float* wc = w6 + (oc * 192 + c) * 9;
#pragma unroll
      for (int ky = 0; ky < 3; ++ky) {
        int iy = oy * 2 + ky - 1;
        if ((unsigned)iy >= 16u) continue;
#pragma unroll
        for (int kx = 0; kx < 3; ++kx) {
          int ix = ox * 2 + kx - 1;
          if ((unsigned)ix >= 16u) continue;
          acc = fmaf(wc[ky * 3 + kx], xc[iy * 16 + ix], acc);
        }
      }
    }
    __shared__ float red[4][64];
    red[cg][pix] = acc;
    __syncthreads();
    if (cg == 0) {
      float s = red[0][pix] + red[1][pix] + red[2][pix] + red[3][pix] + b6[oc];
      F[(84 << 12) + ((oc >> 2) << 8) + (pix << 2) + (oc & 3)] = s;
    }
  }
}

__global__ void k_conv_p7(const float* __restrict__ w, const float* __restrict__ b,
                          float* __restrict__ F) {
  int oc = blockIdx.x;
  int t = threadIdx.x;
  int cg = t >> 4, pix = t & 15;
  int oy = pix >> 2, ox = pix & 3;
  float acc = 0.f;
  int c0 = cg * 16;
  for (int c = c0; c < c0 + 16; ++c) {
#pragma unroll
    for (int ky = 0; ky < 3; ++ky) {
      int iy = oy * 2 + ky - 1;
      if ((unsigned)iy >= 8u) continue;
#pragma unroll
      for (int kx = 0; kx < 3; ++kx) {
        int ix = ox * 2 + kx - 1;
        if ((unsigned)ix >= 8u) continue;
        float xv = fmaxf(F[(84 << 12) + ((c >> 2) << 8) + ((iy * 8 + ix) << 2) + (c & 3)], 0.f);
        acc = fmaf(w[(oc * 64 + c) * 9 + ky * 3 + kx], xv, acc);
      }
    }
  }
  acc += __shfl_down(acc, 32);
  acc += __shfl_down(acc, 16);
  if (cg == 0)
    F[(85 << 12) + ((oc >> 2) << 8) + (pix << 2) + (oc & 3)] = acc + b[oc];
}

// ---------------- BiFPN td / out (K-split x4: one group, 4 K-quarters per block) ----------------
__global__ __launch_bounds__(256) void k_td_t(const float4* __restrict__ F4, float4* __restrict__ TD4,
                     const float* __restrict__ tw, const float* __restrict__ tb,
                     const float* __restrict__ tg, const float* __restrict__ tbt,
                     const float* __restrict__ tm, const float* __restrict__ tv,
                     const float* __restrict__ w1raw, int blk) {
  int bx = blockIdx.x, S = bx * 64;
  int l, off, W, sh; level_of(S, l, off, W, sh);
  int tid = threadIdx.x;
  if (l == 4) {                      // p7td = p7x copy (16 px x 16 c4)
    if (blockIdx.y == 0) {
      int pxrel = tid >> 4, c4 = tid & 15;
      TD4[(85 << 10) + (c4 << 6) + pxrel] = F4[(85 << 10) + (c4 << 6) + pxrel];
    }
    return;
  }
  __shared__ float part[3][8][64];
  float wav = fmaxf(w1raw[blk * 2 + 0], 0.f);
  float wbv = fmaxf(w1raw[blk * 2 + 1], 0.f);
  float s = wav + wbv + 1e-4f;
  wav /= s; wbv /= s;
  int lane = tid & 63;
  int kh = __builtin_amdgcn_readfirstlane(tid >> 6);   // K-quarter 0..3
  int g = blockIdx.y;                // group 0..7
  int ocb = g * 8;
  int px = S + lane;
  int loc = px - off, yy = loc >> sh, xx = loc & (W - 1);
  int Wu = W >> 1;
  int pup = off + W * W + (yy >> 1) * Wu + (xx >> 1);
  int c4base = kh * 4;
  int fup = ((pup >> 6) << 10) + (pup & 63) + (c4base << 6);
  int fself = (bx << 10) + lane + (c4base << 6);
  float acc[8] = {};
  const float4* wt4 = (const float4*)tw + (size_t)((blk * 5 + l) * 64) * 16 + c4base;
#pragma unroll
  for (int c4 = 0; c4 < 4; ++c4) {
    float4 a = F4[fself + (c4 << 6)];
    float4 b = F4[fup + (c4 << 6)];
    float4 fin;
    fin.x = wav * a.x + wbv * b.x; fin.y = wav * a.y + wbv * b.y;
    fin.z = wav * a.z + wbv * b.z; fin.w = wav * a.w + wbv * b.w;
#pragma unroll
    for (int o = 0; o < 8; ++o) {
      float4 wv = wt4[(ocb + o) * 16 + c4];
      acc[o] = fmaf(fin.x, wv.x, fmaf(fin.y, wv.y, fmaf(fin.z, wv.z, fmaf(fin.w, wv.w, acc[o]))));
    }
  }
  if (kh) {
#pragma unroll
    for (int o = 0; o < 8; ++o) part[kh - 1][o][lane] = acc[o];
  }
  __syncthreads();
  if (kh) return;
#pragma unroll
  for (int o = 0; o < 8; ++o)
    acc[o] += part[0][o][lane] + part[1][o][lane] + part[2][o][lane];
  int idxbase = (blk * 5 + l) * 64 + ocb;
#pragma unroll
  for (int q = 0; q < 2; ++q) {
    float r[4];
#pragma unroll
    for (int j = 0; j < 4; ++j) {
      int o = q * 4 + j, idx = idxbase + o;
      float xv = acc[o] + tb[idx];
      float inv = 1.0f / sqrtf(tv[idx] + 4e-5f);
      r[j] = (xv - tm[idx]) * (tg[idx] * inv) + tbt[idx];
    }
    float4 rq; rq.x = r[0]; rq.y = r[1]; rq.z = r[2]; rq.w = r[3];
    TD4[(bx << 10) + (((ocb >> 2) + q) << 6) + lane] = rq;
  }
}

__global__ __launch_bounds__(256) void k_out_t(const float4* __restrict__ F4, const float4* __restrict__ TD4,
                      float4* __restrict__ OUT4,
                      const float* __restrict__ ow, const float* __restrict__ ob,
                      const float* __restrict__ og, const float* __restrict__ obt,
                      const float* __restrict__ om, const float* __restrict__ ov,
                      const float* __restrict__ w2raw, int blk) {
  int bx = blockIdx.x, S = bx * 64;
  int l, off, W, sh; level_of(S, l, off, W, sh);
  int tid = threadIdx.x;
  if (l == 0) {                      // new feats level3 = p3td copy
    if (blockIdx.y == 0)
      for (int j = tid; j < 1024; j += 256)
        OUT4[(bx << 10) + j] = TD4[(bx << 10) + j];
    return;
  }
  __shared__ float part[3][8][64];
  float wav = fmaxf(w2raw[blk * 3 + 0], 0.f);
  float wbv = fmaxf(w2raw[blk * 3 + 1], 0.f);
  float wcv = fmaxf(w2raw[blk * 3 + 2], 0.f);
  float s = wav + wbv + wcv + 1e-4f;
  wav /= s; wbv /= s; wcv /= s;
  int lane = tid & 63;
  int kh = __builtin_amdgcn_readfirstlane(tid >> 6);   // K-quarter 0..3
  int g = blockIdx.y;                // group 0..7
  int ocb = g * 8;
  int px = S + lane;
  bool pxok = px < P_TOT;
  int loc = px - off, yy = loc >> sh, xx = loc & (W - 1);
  int Wd = W << 1;
  int offd = off - Wd * Wd;
  int pdn = offd + (2 * yy) * Wd + 2 * xx;
  int c4base = kh * 4;
  int fself = (bx << 10) + lane + (c4base << 6);
  int fdn = (pxok ? (((pdn >> 6) << 10) + (pdn & 63)) : ((bx << 10) + lane)) + (c4base << 6);
  float acc[8] = {};
  const float4* wt4 = (const float4*)ow + (size_t)((blk * 5 + l) * 64) * 16 + c4base;
#pragma unroll
  for (int c4 = 0; c4 < 4; ++c4) {
    float4 a = F4[fself + (c4 << 6)];
    float4 b = TD4[fself + (c4 << 6)];
    float4 c = TD4[fdn + (c4 << 6)];
    float4 fin;
    fin.x = wav * a.x + wbv * b.x + wcv * c.x;
    fin.y = wav * a.y + wbv * b.y + wcv * c.y;
    fin.z = wav * a.z + wbv * b.z + wcv * c.z;
    fin.w = wav * a.w + wbv * b.w + wcv * c.w;
#pragma unroll
    for (int o = 0; o < 8; ++o) {
      float4 wv = wt4[(ocb + o) * 16 + c4];
      acc[o] = fmaf(fin.x, wv.x, fmaf(fin.y, wv.y, fmaf(fin.z, wv.z, fmaf(fin.w, wv.w, acc[o]))));
    }
  }
  if (kh) {
#pragma unroll
    for (int o = 0; o < 8; ++o) part[kh - 1][o][lane] = acc[o];
  }
  __syncthreads();
  if (kh || !pxok) return;
#pragma unroll
  for (int o = 0; o < 8; ++o)
    acc[o] += part[0][o][lane] + part[1][o][lane] + part[2][o][lane];
  int idxbase = (blk * 5 + l) * 64 + ocb;
#pragma unroll
  for (int q = 0; q < 2; ++q) {
    float r[4];
#pragma unroll
    for (int j = 0; j < 4; ++j) {
      int o = q * 4 + j, idx = idxbase + o;
      float xv = acc[o] + ob[idx];
      float inv = 1.0f / sqrtf(ov[idx] + 4e-5f);
      r[j] = (xv - om[idx]) * (og[idx] * inv) + obt[idx];
    }
    float4 rq; rq.x = r[0]; rq.y = r[1]; rq.z = r[2]; rq.w = r[3];
    OUT4[(bx << 10) + (((ocb >> 2) + q) << 6) + lane] = rq;
  }
}

// ---------------- tap index helper (zero-block for borders) ----------------
__device__ __forceinline__ void tap_idx(int px, int off, int W, int sh, int fidx[9]) {
  int loc = px - off, y = loc >> sh, x = loc & (W - 1);
  int zb = (86 << 10) + (px & 63);
#pragma unroll
  for (int ky = 0; ky < 3; ++ky)
#pragma unroll
    for (int kx = 0; kx < 3; ++kx) {
      int iy = y + ky - 1, ix = x + kx - 1;
      bool v = ((unsigned)iy < (unsigned)W) && ((unsigned)ix < (unsigned)W);
      int pp = px + (ky - 1) * W + (kx - 1);
      fidx[ky * 3 + kx] = v ? (((pp >> 6) << 10) + (pp & 63)) : zb;
    }
}

// merged reg+cls 64->64 layer, K-split x4: block = one group x 4 K-quarters
// g 0-7 -> reg chain, 8-15 -> cls chain
__global__ __launch_bounds__(256) void k_conv3m(const float4* __restrict__ Fr, const float4* __restrict__ Fc,
                        float4* __restrict__ Or, float4* __restrict__ Oc,
                        const float* __restrict__ RWr, const float* __restrict__ RWc,
                        const float* __restrict__ br, const float* __restrict__ bc) {
  __shared__ float part[3][8][64];
  int S = blockIdx.x * 64;
  int l, off, W, sh; level_of(S, l, off, W, sh);
  int lane = threadIdx.x & 63;
  int kh = __builtin_amdgcn_readfirstlane(threadIdx.x >> 6);  // K-quarter 0..3
  int g = blockIdx.y;   // 0..15
  const float4* X; float4* O; const float* RW; const float* bias; int ocb;
  if (g < 8) { X = Fr; O = Or; RW = RWr; bias = br; ocb = g * 8; }
  else       { X = Fc; O = Oc; RW = RWc; bias = bc; ocb = (g - 8) * 8; }
  int px = S + lane;
  int fidx[9];
  tap_idx(px, off, W, sh, fidx);
  float acc[8];
#pragma unroll
  for (int o = 0; o < 8; ++o) acc[o] = 0.f;
  int c4base = kh * 4;
  const float4* W4 = (const float4*)RW + c4base;
#pragma unroll
  for (int t = 0; t < 9; ++t) {
    const float4* wb = W4 + (size_t)(t * 64 + ocb) * 16;
    int fi = fidx[t] + (c4base << 6);
#pragma unroll
    for (int c4 = 0; c4 < 4; ++c4) {
      float4 xv = X[fi + (c4 << 6)];
#pragma unroll
      for (int o = 0; o < 8; ++o) {
        float4 wv = wb[o * 16 + c4];
        acc[o] = fmaf(xv.x, wv.x, fmaf(xv.y, wv.y, fmaf(xv.z, wv.z, fmaf(xv.w, wv.w, acc[o]))));
      }
    }
  }
  if (kh) {
#pragma unroll
    for (int o = 0; o < 8; ++o) part[kh - 1][o][lane] = acc[o];
  }
  __syncthreads();
  if (kh || px >= P_TOT) return;
#pragma unroll
  for (int o = 0; o < 8; ++o)
    acc[o] += part[0][o][lane] + part[1][o][lane] + part[2][o][lane];
#pragma unroll
  for (int q = 0; q < 2; ++q) {
    float4 r;
    r.x = fmaxf(acc[q*4+0] + bias[ocb+q*4+0], 0.f);
    r.y = fmaxf(acc[q*4+1] + bias[ocb+q*4+1], 0.f);
    r.z = fmaxf(acc[q*4+2] + bias[ocb+q*4+2], 0.f);
    r.w = fmaxf(acc[q*4+3] + bias[ocb+q*4+3], 0.f);
    O[(blockIdx.x << 10) + (((ocb >> 2) + q) << 6) + lane] = r;
  }
}

// cls-out (90 groups) + reg-out (5 groups) conv, fused; K-split halves; 2 px/lane.
// Block = 2 groups x 2 K-halves; cls groups write per-anchor max keys to pamax,
// reg groups write REGb directly. key = mono32(logit)<<32 | (127-cls).
__global__ __launch_bounds__(256) void k_conv3c(const float4* __restrict__ Fc, const float4* __restrict__ Fr,
                        const float* __restrict__ RWc, const float* __restrict__ bc,
                        const float* __restrict__ RWr, const float* __restrict__ br,
                        u64* __restrict__ pamax, float* __restrict__ REGb) {
  __shared__ float part[2][8][128];
  int lane = threadIdx.x & 63;
  int wid = __builtin_amdgcn_readfirstlane(threadIdx.x >> 6);
  int gp = wid >> 1, kh = wid & 1;
  int g = blockIdx.y * 2 + gp;          // 0..95
  bool is_cls = g < 90;
  bool is_reg = (g >= 90) && (g < 95);
  int ocb, OCw; const float4* W4; const float4* F4;
  if (is_reg) { ocb = (g - 90) * 8; OCw = 36; W4 = (const float4*)RWr; F4 = Fr; }
  else        { ocb = is_cls ? g * 8 : 0; OCw = 720; W4 = (const float4*)RWc; F4 = Fc; }
  int S = blockIdx.x * 128;
  int px1 = S + lane;              // always < P_TOT (max 5439)
  int px2 = S + 64 + lane;
  bool ok2 = px2 < P_TOT;
  int l, off, W, sh;
  level_of(px1, l, off, W, sh);
  int f1[9];
  tap_idx(px1, off, W, sh, f1);
  int f2[9];
  if (ok2) {
    int l2, off2, W2, sh2;
    level_of(px2, l2, off2, W2, sh2);
    tap_idx(px2, off2, W2, sh2, f2);
  } else {
    int zb = (86 << 10) + lane;
#pragma unroll
    for (int t = 0; t < 9; ++t) f2[t] = zb;
  }
  float a1[8], a2[8];
#pragma unroll
  for (int o = 0; o < 8; ++o) { a1[o] = 0.f; a2[o] = 0.f; }
  int c4base = kh * 8;
  const float4* W4b = W4 + c4base;
#pragma unroll
  for (int t = 0; t < 9; ++t) {
    const float4* wb = W4b + (size_t)(t * OCw + ocb) * 16;
    int fi1 = f1[t] + (c4base << 6), fi2 = f2[t] + (c4base << 6);
#pragma unroll 4
    for (int c4 = 0; c4 < 8; ++c4) {
      float4 x1 = F4[fi1 + (c4 << 6)];
      float4 x2 = F4[fi2 + (c4 << 6)];
#pragma unroll
      for (int o = 0; o < 8; ++o) {
        float4 wv = wb[o * 16 + c4];
        a1[o] = fmaf(x1.x, wv.x, fmaf(x1.y, wv.y, fmaf(x1.z, wv.z, fmaf(x1.w, wv.w, a1[o]))));
        a2[o] = fmaf(x2.x, wv.x, fmaf(x2.y, wv.y, fmaf(x2.z, wv.z, fmaf(x2.w, wv.w, a2[o]))));
      }
    }
  }
  if (kh) {
#pragma unroll
    for (int o = 0; o < 8; ++o) {
      part[gp][o][lane] = a1[o];
      part[gp][o][64 + lane] = a2[o];
    }
  }
  __syncthreads();
  if (kh) return;
#pragma unroll
  for (int o = 0; o < 8; ++o) {
    a1[o] += part[gp][o][lane];
    a2[o] += part[gp][o][64 + lane];
  }
  if (is_cls) {
    int a0 = ocb / 80;
    int cls0 = ocb - a0 * 80;
    u64 k1 = 0ULL, k2 = 0ULL;
#pragma unroll
    for (int o = 0; o < 8; ++o) {
      float bi = bc[ocb + o];
      int cls = cls0 + o;
      u32 low = (u32)(127 - cls);
      float v1 = a1[o] + bi;
      u32 b1 = __float_as_uint(v1);
      b1 = (b1 & 0x80000000u) ? ~b1 : (b1 | 0x80000000u);
      u64 key1 = ((u64)b1 << 32) | low;
      k1 = k1 > key1 ? k1 : key1;
      float v2 = a2[o] + bi;
      u32 b2 = __float_as_uint(v2);
      b2 = (b2 & 0x80000000u) ? ~b2 : (b2 | 0x80000000u);
      u64 key2 = ((u64)b2 << 32) | low;
      k2 = k2 > key2 ? k2 : key2;
    }
    pamax[g * 5504 + px1] = k1;
    if (ok2) pamax[g * 5504 + px2] = k2;
  } else if (is_reg) {
    int nv = (g == 94) ? 4 : 8;
    for (int o = 0; o < nv; ++o) {
      int oc = ocb + o;
      float v1 = a1[o] + br[oc];
      REGb[((size_t)(px1 >> 6) * 9 + (oc >> 2)) * 256 + (px1 & 63) * 4 + (oc & 3)] = v1;
      if (ok2) {
        float v2 = a2[o] + br[oc];
        REGb[((size_t)(px2 >> 6) * 9 + (oc >> 2)) * 256 + (px2 & 63) * 4 + (oc & 3)] = v2;
      }
    }
  }
}

// ---------------- decode boxes + score/label from pamax ----------------
__global__ void k_decode_score(const float4* __restrict__ REG4, const u64* __restrict__ pamax,
                               float* __restrict__ score, int* __restrict__ label,
                               float* __restrict__ boxes, u32* __restrict__ ukey,
                               u32* __restrict__ hist1) {
  int aid = blockIdx.x * 256 + threadIdx.x;
  if (aid >= NANCH) return;
  int p = aid / 9;
  int a = aid - p * 9;
  int l, off, W, sh; level_of(p, l, off, W, sh);
  int loc = p - off, y = loc >> sh, x = loc & (W - 1);
  int s_idx = a % 3, r_idx = a / 3;
  double scale = (s_idx == 0) ? 1.0 : ((s_idx == 1) ? 1.2599210498948732 : 1.5874010519681994);
  double ratio = (r_idx == 0) ? 0.5 : ((r_idx == 1) ? 1.0 : 2.0);
  double strided = (double)(8 << l);
  double based = (double)(32 << l);
  double w0 = based * scale;
  double wA = sqrt(w0 * w0 / ratio);
  double hA = wA * ratio;
  double cxd = (x + 0.5) * strided;
  double cyd = (y + 0.5) * strided;
  float ax1 = (float)(cxd - wA / 2.0);
  float ay1 = (float)(cyd - hA / 2.0);
  float ax2 = (float)(cxd + wA / 2.0);
  float ay2 = (float)(cyd + hA / 2.0);
  float wa = ax2 - ax1, ha = ay2 - ay1;
  float cxa = ax1 + 0.5f * wa, cya = ay1 + 0.5f * ha;
  int blk = p >> 6, pxin = p & 63;
  float4 rq = REG4[blk * 576 + (a << 6) + pxin];
  float ncx = cxa + (rq.x * 0.1f) * wa;
  float ncy = cya + (rq.y * 0.1f) * ha;
  float nw = expf(rq.z * 0.2f) * wa;
  float nh = expf(rq.w * 0.2f) * ha;
  float bx1 = fmaxf(ncx - 0.5f * nw, 0.f);
  float by1 = fmaxf(ncy - 0.5f * nh, 0.f);
  float bx2 = fminf(ncx + 0.5f * nw, 512.f);
  float by2 = fminf(ncy + 0.5f * nh, 512.f);
  boxes[aid * 4 + 0] = bx1; boxes[aid * 4 + 1] = by1;
  boxes[aid * 4 + 2] = bx2; boxes[aid * 4 + 3] = by2;
  u64 key = 0ULL;
  const u64* pa = pamax + (size_t)(a * 10) * 5504 + p;
#pragma unroll
  for (int gi = 0; gi < 10; ++gi) {
    u64 k = pa[gi * 5504];
    key = key > k ? key : k;
  }
  u32 b = (u32)(key >> 32);
  b = (b & 0x80000000u) ? (b & 0x7FFFFFFFu) : ~b;
  float best = __uint_as_float(b);
  int bl = 127 - (int)(key & 0xFFFFFFFFu);
  float sc = 1.f / (1.f + expf(-best));
  score[aid] = sc; label[aid] = bl;
  u32 u = 0u;
  if (sc > 0.05f) u = __float_as_uint(sc) | 0x80000000u;
  ukey[aid] = u;
  if (u) atomicAdd(&hist1[u >> 16], 1u);
}

// ---------------- radix-select scans ----------------
__global__ __launch_bounds__(1024) void k_scanA(const u32* __restrict__ hist, u32* __restrict__ ctrl) {
  __shared__ u32 cs[1024];
  u32 s = 0;
  int base = threadIdx.x * 64;
  for (int b = 0; b < 64; ++b) s += hist[base + b];
  cs[threadIdx.x] = s;
  __syncthreads();
  if (threadIdx.x == 0) {
    u32 cum = 0; int cc = -1;
    for (int tt = 1023; tt >= 0; --tt) {
      if (cum + cs[tt] >= (u32)KTOP) { cc = tt; break; }
      cum += cs[tt];
    }
    if (cc < 0) {
      ctrl[0] = 0x20000u; ctrl[1] = cum; ctrl[2] = 1u;
    } else {
      u32 c2 = cum; int B1 = cc * 64; u32 hB1 = 0;
      for (int b = cc * 64 + 63; b >= cc * 64; --b) {
        u32 h = hist[b];
        if (c2 + h >= (u32)KTOP) { B1 = b; hB1 = h; break; }
        c2 += h;
      }
      ctrl[0] = (u32)B1; ctrl[1] = c2;
      if (c2 + hB1 <= (u32)CAND_CAP) {   // whole bucket fits: skip pass 2
        ctrl[2] = (u32)B1 << 16;
        ctrl[5] = 1u;
      }
    }
  }
}

__global__ void k_histB(const u32* __restrict__ ukey, u32* __restrict__ hist2,
                        const u32* __restrict__ ctrl) {
  if (ctrl[5]) return;
  int aid = blockIdx.x * 256 + threadIdx.x;
  if (aid >= NANCH) return;
  u32 u = ukey[aid];
  if (u && (u >> 16) == ctrl[0]) atomicAdd(&hist2[u & 0xFFFFu], 1u);
}

__global__ __launch_bounds__(1024) void k_scanB(const u32* __restrict__ hist, u32* __restrict__ ctrl) {
  if (ctrl[0] > 0xFFFFu || ctrl[5]) return;
  __shared__ u32 cs[1024];
  u32 s = 0;
  int base = threadIdx.x * 64;
  for (int b = 0; b < 64; ++b) s += hist[base + b];
  cs[threadIdx.x] = s;
  __syncthreads();
  if (threadIdx.x == 0) {
    u32 CA = ctrl[1];
    u32 cum = CA; int cc = -1;
    for (int tt = 1023; tt >= 0; --tt) {
      if (cum + cs[tt] >= (u32)KTOP) { cc = tt; break; }
      cum += cs[tt];
    }
    u32 B2 = 0;
    if (cc >= 0) {
      for (int b = cc * 64 + 63; b >= cc * 64; --b) {
        u32 h = hist[b];
        if (cum + h >= (u32)KTOP) { B2 = (u32)b; break; }
        cum += h;
      }
    }
    ctrl[2] = (ctrl[0] << 16) | B2;
  }
}

__global__ void k_compact(const u32* __restrict__ ukey, u64* __restrict__ cand,
                          u32* __restrict__ ctrl) {
  int aid = blockIdx.x * 256 + threadIdx.x;
  if (aid >= NANCH) return;
  u32 u = ukey[aid];
  u32 T = ctrl[2];
  if (u >= T && u != 0) {
    u32 pos = atomicAdd(&ctrl[3], 1u);
    if (pos < (u32)CAND_CAP)
      cand[pos] = (((u64)u) << 32) | (u32)(~(u32)aid);
  }
}

// ---------------- bitonic sort + select top-1000 ----------------
__global__ __launch_bounds__(1024) void k_sortsel(const u64* __restrict__ cand, u32* __restrict__ ctrl,
                                                  const float* __restrict__ score, const int* __restrict__ label,
                                                  const float* __restrict__ boxes,
                                                  float* __restrict__ tops, int* __restrict__ topl,
                                                  float* __restrict__ topb) {
  __shared__ u64 key[CAND_CAP];
  int C = min((int)ctrl[3], CAND_CAP);
  for (int i = threadIdx.x; i < CAND_CAP; i += 1024) key[i] = (i < C) ? cand[i] : 0ULL;
  __syncthreads();
  for (int k = 2; k <= CAND_CAP; k <<= 1) {
    for (int j = k >> 1; j > 0; j >>= 1) {
      for (int t = threadIdx.x; t < CAND_CAP / 2; t += 1024) {
        int i1 = ((t & ~(j - 1)) << 1) | (t & (j - 1));
        int i2 = i1 + j;
        bool up = (i1 & k) != 0;
        u64 a = key[i1], b = key[i2];
        bool sw = up ? (a > b) : (a < b);
        if (sw) { key[i1] = b; key[i2] = a; }
      }
      __syncthreads();
    }
  }
  if (threadIdx.x < KTOP) {
    int r = threadIdx.x;
    u64 kk = key[r];
    u32 u = (u32)(kk >> 32);
    if (u != 0) {
      int aid = (int)(~((u32)kk));
      float sv = __uint_as_float(u & 0x7FFFFFFFu);
      tops[r] = sv; topl[r] = label[aid];
      topb[r * 4 + 0] = boxes[aid * 4 + 0];
      topb[r * 4 + 1] = boxes[aid * 4 + 1];
      topb[r * 4 + 2] = boxes[aid * 4 + 2];
      topb[r * 4 + 3] = boxes[aid * 4 + 3];
    } else {
      tops[r] = -1.f; topl[r] = -1;
      topb[r * 4 + 0] = 0.f; topb[r * 4 + 1] = 0.f;
      topb[r * 4 + 2] = 0.f; topb[r * 4 + 3] = 0.f;
    }
  }
  if (threadIdx.x == 0) ctrl[4] = (u32)min(C, KTOP);
}

// ---------------- NMS ----------------
__global__ void k_iou(const float* __restrict__ topb, const u32* __restrict__ ctrl,
                      u64* __restrict__ mask) {
  int wid = threadIdx.x >> 6, lane = threadIdx.x & 63;
  int i = blockIdx.x * 4 + wid;
  int V = (int)ctrl[4];
  if (i >= V) return;
  float x1i = topb[i * 4], y1i = topb[i * 4 + 1], x2i = topb[i * 4 + 2], y2i = topb[i * 4 + 3];
  float ai = fmaxf(x2i - x1i, 0.f) * fmaxf(y2i - y1i, 0.f);
  for (int w = 0; w < 16; ++w) {
    int j = w * 64 + lane;
    bool bit = false;
    if (j < KTOP && j > i) {
      float x1j = topb[j * 4], y1j = topb[j * 4 + 1], x2j = topb[j * 4 + 2], y2j = topb[j * 4 + 3];
      float aj = fmaxf(x2j - x1j, 0.f) * fmaxf(y2j - y1j, 0.f);
      float iw = fmaxf(fminf(x2i, x2j) - fmaxf(x1i, x1j), 0.f);
      float ih = fmaxf(fminf(y2i, y2j) - fmaxf(y1i, y1j), 0.f);
      float inter = iw * ih;
      float iou = inter / (ai + aj - inter + 1e-8f);
      bit = iou > 0.5f;
    }
    u64 m = __ballot(bit);
    if (lane == 0) mask[i * 16 + w] = m;
  }
}

// NMS scan (wave 0) + final output (all 256 threads), fused
__global__ __launch_bounds__(256) void k_nmsfinal(const u64* __restrict__ mask,
                                                  const float* __restrict__ tops,
                                                  const int* __restrict__ topl,
                                                  const float* __restrict__ topb,
                                                  float* __restrict__ out) {
  __shared__ char kf[KTOP];
  int tid = threadIdx.x;
  if (tid < 64) {
    const int la = tid;
    const int rg = la >> 4;
    const int wg = la & 15;
    u64 remw = 0ULL;

#define LOADB(b, upd, intra, vsc) do {                                   \
    int rb = (b) * 64;                                                   \
    _Pragma("unroll")                                                    \
    for (int k = 0; k < 16; ++k)                                         \
      upd[k] = mask[(u32)(rb + rg + 4 * k) * 16u + (u32)wg];             \
    intra = mask[(u32)(rb + la) * 16u + (u32)(b)];                       \
    vsc = tops[rb + la];                                                 \
  } while (0)

#define PROC(b, upd, intra, vsc) do {                                    \
    u64 validmask = __ballot((vsc) > 0.05f);                             \
    u32 ilo = (u32)(intra);                                              \
    u32 ihi = (u32)((intra) >> 32);                                      \
    u64 supmask = ((u64)__builtin_amdgcn_readlane((int)(remw >> 32), (b)) << 32) | \
                  (u32)__builtin_amdgcn_readlane((int)(u32)remw, (b));   \
    u64 keptmask = 0ULL;                                                 \
    for (int i = 0; i < 64; ++i) {                                       \
      u32 rlo = (u32)__builtin_amdgcn_readlane((int)ilo, i);             \
      u32 rhi = (u32)__builtin_amdgcn_readlane((int)ihi, i);             \
      u64 take = (u64)0 - (((validmask >> i) & 1ULL) & (~(supmask >> i) & 1ULL)); \
      keptmask |= (1ULL << i) & take;                                    \
      supmask |= (((u64)rhi << 32) | rlo) & take;                       \
    }                                                                    \
    u64 kk = keptmask >> rg;                                             \
    u64 acc = 0ULL;                                                      \
    _Pragma("unroll")                                                    \
    for (int k = 0; k < 16; ++k)                                         \
      if ((kk >> (4 * k)) & 1ULL) acc |= upd[k];                         \
    acc |= __shfl_xor(acc, 16);                                          \
    acc |= __shfl_xor(acc, 32);                                          \
    remw |= acc;                                                         \
    int j = (b) * 64 + la;                                               \
    if (j < KTOP) kf[j] = (char)((keptmask >> la) & 1ULL);               \
  } while (0)

    u64 updA[16], updB[16];
    u64 intraA, intraB;
    float vscA, vscB;
    LOADB(0, updA, intraA, vscA);
    for (int bb = 0; bb < 16; bb += 2) {
      if (bb + 1 < 16) LOADB(bb + 1, updB, intraB, vscB);
      PROC(bb, updA, intraA, vscA);
      if (bb + 2 < 16) LOADB(bb + 2, updA, intraA, vscA);
      if (bb + 1 < 16) PROC(bb + 1, updB, intraB, vscB);
    }
#undef LOADB
#undef PROC
  }
  __syncthreads();
  for (int r = tid; r < KTOP; r += 256) {
    int k = kf[r];
    out[r] = k ? tops[r] : 0.f;
    out[KTOP + r] = k ? (float)topl[r] : -1.f;
    out[2 * KTOP + r * 4 + 0] = k ? topb[r * 4 + 0] : 0.f;
    out[2 * KTOP + r * 4 + 1] = k ? topb[r * 4 + 1] : 0.f;
    out[2 * KTOP + r * 4 + 2] = k ? topb[r * 4 + 2] : 0.f;
    out[2 * KTOP + r * 4 + 3] = k ? topb[r * 4 + 3] : 0.f;
  }
}

extern "C" void kernel_launch(void* const* d_in, const int* in_sizes, int n_in,
                              void* d_out, int out_size, void* d_ws, size_t ws_size,
                              hipStream_t stream) {
  const float* c3    = (const float*)d_in[0];
  const float* c4i   = (const float*)d_in[1];
  const float* c5    = (const float*)d_in[2];
  const float* w3    = (const float*)d_in[3];  const float* b3 = (const float*)d_in[4];
  const float* w4    = (const float*)d_in[5];  const float* b4 = (const float*)d_in[6];
  const float* w5    = (const float*)d_in[7];  const float* b5 = (const float*)d_in[8];
  const float* w6    = (const float*)d_in[9];  const float* b6 = (const float*)d_in[10];
  const float* w7    = (const float*)d_in[11]; const float* b7 = (const float*)d_in[12];
  const float* tdw   = (const float*)d_in[13]; const float* tdb  = (const float*)d_in[14];
  const float* tdg   = (const float*)d_in[15]; const float* tdbt = (const float*)d_in[16];
  const float* tdm   = (const float*)d_in[17]; const float* tdv  = (const float*)d_in[18];
  const float* ow    = (const float*)d_in[19]; const float* ob   = (const float*)d_in[20];
  const float* og    = (const float*)d_in[21]; const float* obt  = (const float*)d_in[22];
  const float* om    = (const float*)d_in[23]; const float* ov   = (const float*)d_in[24];
  const float* w1    = (const float*)d_in[25]; const float* w2   = (const float*)d_in[26];
  const float* clsw  = (const float*)d_in[27]; const float* clsb = (const float*)d_in[28];
  const float* clsow = (const float*)d_in[29]; const float* clsob= (const float*)d_in[30];
  const float* regw  = (const float*)d_in[31]; const float* regb = (const float*)d_in[32];
  const float* regow = (const float*)d_in[33]; const float* regob= (const float*)d_in[34];

  float* ws = (float*)d_ws;
  const size_t NF = 356352;                 // 87 blks * 4096 floats (blk 86 = zeros)
  float* A    = ws;
  float* Bb   = ws + NF;
  float* Cb   = ws + 2 * NF;
  float* Db   = ws + 3 * NF;
  float* RWc  = ws + 4 * NF;                // 110592
  float* RWco = RWc + 110592;               // 414720
  float* RWr  = RWco + 414720;              // 110592
  float* RWro = RWr + 110592;               // 20736 + 1024 pad
  float* REGb = RWro + 21760;               // 198144 (86*2304)
  u64*   pamax = (u64*)(REGb + 198144);     // 90*5504 u64 = 495360
  float* scoreb = (float*)(pamax + 495360); // 49104
  int*   labelb = (int*)(scoreb + 49104);   // 49104
  float* boxesb = (float*)(labelb + 49104); // 196416
  u32* hist1 = (u32*)(boxesb + 196416);     // 65536
  u32* hist2 = hist1 + 65536;               // 65536
  u32* ctrl  = hist2 + 65536;               // 64
  u64* cand  = (u64*)(ctrl + 64);           // 2048 u64
  float* tops = (float*)(cand + CAND_CAP);  // 1024
  int*   topl = (int*)(tops + 1024);        // 1024
  float* topb = (float*)(topl + 1024);      // 4096
  u64*   mask = (u64*)(topb + 4096);        // 16384 u64
  u32*   ukeyb = (u32*)(mask + 16384);      // 49104

  float4* A4 = (float4*)A; float4* B4 = (float4*)Bb;
  float4* C4 = (float4*)Cb; float4* D4 = (float4*)Db;
  float4* REG4 = (float4*)REGb;

  // prep: repack all head weights + zero hist/ctrl/zero-blocks/RWro-pad
  k_prep<<<dim3(3146), 256, 0, stream>>>(clsw, regw, clsow, regow, RWc, RWr, RWco, RWro,
                                         hist1, A, Bb, Cb, Db);

  // FPN inputs (batch 0 only) -> blocked layout, into A
  k_fpn_in<<<dim3(448), 256, 0, stream>>>(c3, w3, b3, c4i, w4, b4, c5, w5, b5, w6, b6, A, A4);
  k_conv_p7<<<dim3(64), 64, 0, stream>>>(w7, b7, A);

  // BiFPN x2 (read/write disjoint per kernel; K-split x4)
  k_td_t<<<dim3(86, 8), 256, 0, stream>>>(A4, B4, tdw, tdb, tdg, tdbt, tdm, tdv, w1, 0);
  k_out_t<<<dim3(86, 8), 256, 0, stream>>>(A4, B4, C4, ow, ob, og, obt, om, ov, w2, 0);
  k_td_t<<<dim3(86, 8), 256, 0, stream>>>(C4, B4, tdw, tdb, tdg, tdbt, tdm, tdv, w1, 1);
  k_out_t<<<dim3(86, 8), 256, 0, stream>>>(C4, B4, A4, ow, ob, og, obt, om, ov, w2, 1);

  // heads: merged reg+cls 64->64 layers (K-split x4), 4-buffer rotation
  k_conv3m<<<dim3(86, 16), 256, 0, stream>>>(A4, A4, C4, D4, RWr, RWc, regb, clsb);
  k_conv3m<<<dim3(86, 16), 256, 0, stream>>>(C4, D4, B4, A4, RWr + 36864, RWc + 36864, regb + 64, clsb + 64);
  k_conv3m<<<dim3(86, 16), 256, 0, stream>>>(B4, A4, C4, D4, RWr + 73728, RWc + 73728, regb + 128, clsb + 128);
  // reg final features in Cb, cls final features in Db; fused cls-out + reg-out (R10 shape)
  k_conv3c<<<dim3(43, 48), 256, 0, stream>>>(D4, C4, RWco, clsob, RWro, regob, pamax, REGb);

  // decode + score + top-k + NMS
  k_decode_score<<<dim3(192), 256, 0, stream>>>(REG4, pamax, scoreb, labelb, boxesb, ukeyb, hist1);
  k_scanA<<<dim3(1), 1024, 0, stream>>>(hist1, ctrl);
  k_histB<<<dim3(192), 256, 0, stream>>>(ukeyb, hist2, ctrl);
  k_scanB<<<dim3(1), 1024, 0, stream>>>(hist2, ctrl);
  k_compact<<<dim3(192), 256, 0, stream>>>(ukeyb, cand, ctrl);
  k_sortsel<<<dim3(1), 1024, 0, stream>>>(cand, ctrl, scoreb, labelb, boxesb, tops, topl, topb);
  k_iou<<<dim3(250), 256, 0, stream>>>(topb, ctrl, mask);
  k_nmsfinal<<<dim3(1), 256, 0, stream>>>(mask, tops, topl, topb, (float*)d_out);
}

// Round 13
// 416.591 us; speedup vs baseline: 1.2000x; 1.0112x over previous
//
#include <hip/hip_runtime.h>

#define P_TOT 5456
#define NANCH 49104
#define KTOP 1000
#define CAND_CAP 2048

typedef unsigned long long u64;
typedef unsigned int u32;

// Blocked-transposed feature layout: float4 index = blk*1024 + c4*64 + pxin
// Block 86 of each feature buffer is all-zeros (border-tap target).
// Buffer rotation (race-free): every kernel's read-set and write-set are disjoint.

__device__ __forceinline__ void level_of(int p, int& l, int& off, int& W, int& sh) {
  if (p < 4096)      { l = 0; off = 0;    W = 64; sh = 6; }
  else if (p < 5120) { l = 1; off = 4096; W = 32; sh = 5; }
  else if (p < 5376) { l = 2; off = 5120; W = 16; sh = 4; }
  else if (p < 5440) { l = 3; off = 5376; W = 8;  sh = 3; }
  else               { l = 4; off = 5440; W = 4;  sh = 2; }
}

// ---------------- prep: weight repack + all zero-inits ----------------
__global__ void k_prep(const float* __restrict__ clsw, const float* __restrict__ regw,
                       const float* __restrict__ clsow, const float* __restrict__ regow,
                       float* __restrict__ RWc, float* __restrict__ RWr,
                       float* __restrict__ RWco, float* __restrict__ RWro,
                       u32* __restrict__ zhist, float* __restrict__ A, float* __restrict__ Bb,
                       float* __restrict__ Cb, float* __restrict__ Db) {
  int idx = blockIdx.x * 256 + threadIdx.x;
  if (idx < 656640) {
    const float* src; float* dst; int OC, local;
    if (idx < 110592)      { src = clsw;  dst = RWc;  OC = 64;  local = idx; }
    else if (idx < 221184) { src = regw;  dst = RWr;  OC = 64;  local = idx - 110592; }
    else if (idx < 635904) { src = clsow; dst = RWco; OC = 720; local = idx - 221184; }
    else                   { src = regow; dst = RWro; OC = 36;  local = idx - 635904; }
    int per = OC * 576;
    int layer = local / per;
    int rem = local - layer * per;
    int oc = rem / 576;
    int r2 = rem - oc * 576;
    int c = r2 / 9;
    int k = r2 - c * 9;
    dst[layer * per + (k * OC + oc) * 64 + c] = src[local];
    return;
  }
  int z = idx - 656640;
  if (z < 131136) { zhist[z] = 0; return; }      // hist1 + hist2 + ctrl
  z -= 131136;
  if (z < 16384) {
    float* buf = (z < 4096) ? A : (z < 8192) ? Bb : (z < 12288) ? Cb : Db;
    buf[86 * 4096 + (z & 4095)] = 0.f;
    return;
  }
  z -= 16384;
  if (z < 1024) RWro[20736 + z] = 0.f;           // RWro pad (OOB-read safety)
}

// ---------------- fused FPN input convs (c3, c4, c5 1x1 + p6) ----------------
__global__ void k_fpn_in(const float* __restrict__ c3, const float* __restrict__ w3, const float* __restrict__ b3,
                         const float* __restrict__ c4i, const float* __restrict__ w4, const float* __restrict__ b4,
                         const float* __restrict__ c5, const float* __restrict__ w5, const float* __restrict__ b5,
                         const float* __restrict__ w6, const float* __restrict__ b6,
                         float* __restrict__ F, float4* __restrict__ F4) {
  int bx = blockIdx.x;
  if (bx < 320) {        // 1x1 convs (c3: blocks 0..255, c4: 256..319)
    const float* x; const float* w; const float* b; int Cin, npix, off, c4o, p;
    if (bx < 256) { x = c3; w = w3; b = b3; Cin = 40; npix = 4096; off = 0;
                    c4o = bx >> 4; p = (bx & 15) * 256 + threadIdx.x; }
    else          { int lo = bx - 256; x = c4i; w = w4; b = b4; Cin = 80; npix = 1024; off = 4096;
                    c4o = lo >> 2; p = (lo & 3) * 256 + threadIdx.x; }
    int oc4 = c4o * 4;
    float acc[4] = {0.f,0.f,0.f,0.f};
    for (int c = 0; c < Cin; ++c) {
      float xv = x[c * npix + p];
#pragma unroll
      for (int o = 0; o < 4; ++o)
        acc[o] = fmaf(w[(oc4 + o) * Cin + c], xv, acc[o]);
    }
    int px = off + p;
    float4 r;
    r.x = acc[0] + b[oc4 + 0]; r.y = acc[1] + b[oc4 + 1];
    r.z = acc[2] + b[oc4 + 2]; r.w = acc[3] + b[oc4 + 3];
    F4[((px >> 6) << 10) + (c4o << 6) + (px & 63)] = r;
  } else if (bx < 384) { // c5 1x1: one oc per block, 256 px
    int oc = bx - 320;
    int p = threadIdx.x;
    float acc = 0.f;
    for (int c = 0; c < 192; ++c)
      acc = fmaf(w5[oc * 192 + c], c5[c * 256 + p], acc);
    int px = 5120 + p;
    F[((px >> 6) << 12) + ((oc >> 2) << 8) + ((px & 63) << 2) + (oc & 3)] = acc + b5[oc];
  } else {               // p6 conv 3x3 s2: one oc per block
    int oc = bx - 384;
    int tid = threadIdx.x;
    int cg = tid >> 6, pix = tid & 63;
    int oy = pix >> 3, ox = pix & 7;
    float acc = 0.f;
    int c0 = cg * 48;
    for (int c = c0; c < c0 + 48; ++c) {
      const float* xc = c5 + c * 256;
      const float* wc = w6 + (oc * 192 + c) * 9;
#pragma unroll
      for (int ky = 0; ky < 3; ++ky) {
        int iy = oy * 2 + ky - 1;
        if ((unsigned)iy >= 16u) continue;
#pragma unroll
        for (int kx = 0; kx < 3; ++kx) {
          int ix = ox * 2 + kx - 1;
          if ((unsigned)ix >= 16u) continue;
          acc = fmaf(wc[ky * 3 + kx], xc[iy * 16 + ix], acc);
        }
      }
    }
    __shared__ float red[4][64];
    red[cg][pix] = acc;
    __syncthreads();
    if (cg == 0) {
      float s = red[0][pix] + red[1][pix] + red[2][pix] + red[3][pix] + b6[oc];
      F[(84 << 12) + ((oc >> 2) << 8) + (pix << 2) + (oc & 3)] = s;
    }
  }
}

__global__ void k_conv_p7(const float* __restrict__ w, const float* __restrict__ b,
                          float* __restrict__ F) {
  int oc = blockIdx.x;
  int t = threadIdx.x;
  int cg = t >> 4, pix = t & 15;
  int oy = pix >> 2, ox = pix & 3;
  float acc = 0.f;
  int c0 = cg * 16;
  for (int c = c0; c < c0 + 16; ++c) {
#pragma unroll
    for (int ky = 0; ky < 3; ++ky) {
      int iy = oy * 2 + ky - 1;
      if ((unsigned)iy >= 8u) continue;
#pragma unroll
      for (int kx = 0; kx < 3; ++kx) {
        int ix = ox * 2 + kx - 1;
        if ((unsigned)ix >= 8u) continue;
        float xv = fmaxf(F[(84 << 12) + ((c >> 2) << 8) + ((iy * 8 + ix) << 2) + (c & 3)], 0.f);
        acc = fmaf(w[(oc * 64 + c) * 9 + ky * 3 + kx], xv, acc);
      }
    }
  }
  acc += __shfl_down(acc, 32);
  acc += __shfl_down(acc, 16);
  if (cg == 0)
    F[(85 << 12) + ((oc >> 2) << 8) + (pix << 2) + (oc & 3)] = acc + b[oc];
}

// ---------------- BiFPN td / out (K-split x4: one group, 4 K-quarters per block) ----------------
__global__ __launch_bounds__(256) void k_td_t(const float4* __restrict__ F4, float4* __restrict__ TD4,
                     const float* __restrict__ tw, const float* __restrict__ tb,
                     const float* __restrict__ tg, const float* __restrict__ tbt,
                     const float* __restrict__ tm, const float* __restrict__ tv,
                     const float* __restrict__ w1raw, int blk) {
  int bx = blockIdx.x, S = bx * 64;
  int l, off, W, sh; level_of(S, l, off, W, sh);
  int tid = threadIdx.x;
  if (l == 4) {                      // p7td = p7x copy (16 px x 16 c4)
    if (blockIdx.y == 0) {
      int pxrel = tid >> 4, c4 = tid & 15;
      TD4[(85 << 10) + (c4 << 6) + pxrel] = F4[(85 << 10) + (c4 << 6) + pxrel];
    }
    return;
  }
  __shared__ float part[3][8][64];
  float wav = fmaxf(w1raw[blk * 2 + 0], 0.f);
  float wbv = fmaxf(w1raw[blk * 2 + 1], 0.f);
  float s = wav + wbv + 1e-4f;
  wav /= s; wbv /= s;
  int lane = tid & 63;
  int kh = __builtin_amdgcn_readfirstlane(tid >> 6);   // K-quarter 0..3
  int g = blockIdx.y;                // group 0..7
  int ocb = g * 8;
  int px = S + lane;
  int loc = px - off, yy = loc >> sh, xx = loc & (W - 1);
  int Wu = W >> 1;
  int pup = off + W * W + (yy >> 1) * Wu + (xx >> 1);
  int c4base = kh * 4;
  int fup = ((pup >> 6) << 10) + (pup & 63) + (c4base << 6);
  int fself = (bx << 10) + lane + (c4base << 6);
  float acc[8] = {};
  const float4* wt4 = (const float4*)tw + (size_t)((blk * 5 + l) * 64) * 16 + c4base;
#pragma unroll
  for (int c4 = 0; c4 < 4; ++c4) {
    float4 a = F4[fself + (c4 << 6)];
    float4 b = F4[fup + (c4 << 6)];
    float4 fin;
    fin.x = wav * a.x + wbv * b.x; fin.y = wav * a.y + wbv * b.y;
    fin.z = wav * a.z + wbv * b.z; fin.w = wav * a.w + wbv * b.w;
#pragma unroll
    for (int o = 0; o < 8; ++o) {
      float4 wv = wt4[(ocb + o) * 16 + c4];
      acc[o] = fmaf(fin.x, wv.x, fmaf(fin.y, wv.y, fmaf(fin.z, wv.z, fmaf(fin.w, wv.w, acc[o]))));
    }
  }
  if (kh) {
#pragma unroll
    for (int o = 0; o < 8; ++o) part[kh - 1][o][lane] = acc[o];
  }
  __syncthreads();
  if (kh) return;
#pragma unroll
  for (int o = 0; o < 8; ++o)
    acc[o] += part[0][o][lane] + part[1][o][lane] + part[2][o][lane];
  int idxbase = (blk * 5 + l) * 64 + ocb;
#pragma unroll
  for (int q = 0; q < 2; ++q) {
    float r[4];
#pragma unroll
    for (int j = 0; j < 4; ++j) {
      int o = q * 4 + j, idx = idxbase + o;
      float xv = acc[o] + tb[idx];
      float inv = 1.0f / sqrtf(tv[idx] + 4e-5f);
      r[j] = (xv - tm[idx]) * (tg[idx] * inv) + tbt[idx];
    }
    float4 rq; rq.x = r[0]; rq.y = r[1]; rq.z = r[2]; rq.w = r[3];
    TD4[(bx << 10) + (((ocb >> 2) + q) << 6) + lane] = rq;
  }
}

__global__ __launch_bounds__(256) void k_out_t(const float4* __restrict__ F4, const float4* __restrict__ TD4,
                      float4* __restrict__ OUT4,
                      const float* __restrict__ ow, const float* __restrict__ ob,
                      const float* __restrict__ og, const float* __restrict__ obt,
                      const float* __restrict__ om, const float* __restrict__ ov,
                      const float* __restrict__ w2raw, int blk) {
  int bx = blockIdx.x, S = bx * 64;
  int l, off, W, sh; level_of(S, l, off, W, sh);
  int tid = threadIdx.x;
  if (l == 0) {                      // new feats level3 = p3td copy
    if (blockIdx.y == 0)
      for (int j = tid; j < 1024; j += 256)
        OUT4[(bx << 10) + j] = TD4[(bx << 10) + j];
    return;
  }
  __shared__ float part[3][8][64];
  float wav = fmaxf(w2raw[blk * 3 + 0], 0.f);
  float wbv = fmaxf(w2raw[blk * 3 + 1], 0.f);
  float wcv = fmaxf(w2raw[blk * 3 + 2], 0.f);
  float s = wav + wbv + wcv + 1e-4f;
  wav /= s; wbv /= s; wcv /= s;
  int lane = tid & 63;
  int kh = __builtin_amdgcn_readfirstlane(tid >> 6);   // K-quarter 0..3
  int g = blockIdx.y;                // group 0..7
  int ocb = g * 8;
  int px = S + lane;
  bool pxok = px < P_TOT;
  int loc = px - off, yy = loc >> sh, xx = loc & (W - 1);
  int Wd = W << 1;
  int offd = off - Wd * Wd;
  int pdn = offd + (2 * yy) * Wd + 2 * xx;
  int c4base = kh * 4;
  int fself = (bx << 10) + lane + (c4base << 6);
  int fdn = (pxok ? (((pdn >> 6) << 10) + (pdn & 63)) : ((bx << 10) + lane)) + (c4base << 6);
  float acc[8] = {};
  const float4* wt4 = (const float4*)ow + (size_t)((blk * 5 + l) * 64) * 16 + c4base;
#pragma unroll
  for (int c4 = 0; c4 < 4; ++c4) {
    float4 a = F4[fself + (c4 << 6)];
    float4 b = TD4[fself + (c4 << 6)];
    float4 c = TD4[fdn + (c4 << 6)];
    float4 fin;
    fin.x = wav * a.x + wbv * b.x + wcv * c.x;
    fin.y = wav * a.y + wbv * b.y + wcv * c.y;
    fin.z = wav * a.z + wbv * b.z + wcv * c.z;
    fin.w = wav * a.w + wbv * b.w + wcv * c.w;
#pragma unroll
    for (int o = 0; o < 8; ++o) {
      float4 wv = wt4[(ocb + o) * 16 + c4];
      acc[o] = fmaf(fin.x, wv.x, fmaf(fin.y, wv.y, fmaf(fin.z, wv.z, fmaf(fin.w, wv.w, acc[o]))));
    }
  }
  if (kh) {
#pragma unroll
    for (int o = 0; o < 8; ++o) part[kh - 1][o][lane] = acc[o];
  }
  __syncthreads();
  if (kh || !pxok) return;
#pragma unroll
  for (int o = 0; o < 8; ++o)
    acc[o] += part[0][o][lane] + part[1][o][lane] + part[2][o][lane];
  int idxbase = (blk * 5 + l) * 64 + ocb;
#pragma unroll
  for (int q = 0; q < 2; ++q) {
    float r[4];
#pragma unroll
    for (int j = 0; j < 4; ++j) {
      int o = q * 4 + j, idx = idxbase + o;
      float xv = acc[o] + ob[idx];
      float inv = 1.0f / sqrtf(ov[idx] + 4e-5f);
      r[j] = (xv - om[idx]) * (og[idx] * inv) + obt[idx];
    }
    float4 rq; rq.x = r[0]; rq.y = r[1]; rq.z = r[2]; rq.w = r[3];
    OUT4[(bx << 10) + (((ocb >> 2) + q) << 6) + lane] = rq;
  }
}

// ---------------- tap index helper (zero-block for borders) ----------------
__device__ __forceinline__ void tap_idx(int px, int off, int W, int sh, int fidx[9]) {
  int loc = px - off, y = loc >> sh, x = loc & (W - 1);
  int zb = (86 << 10) + (px & 63);
#pragma unroll
  for (int ky = 0; ky < 3; ++ky)
#pragma unroll
    for (int kx = 0; kx < 3; ++kx) {
      int iy = y + ky - 1, ix = x + kx - 1;
      bool v = ((unsigned)iy < (unsigned)W) && ((unsigned)ix < (unsigned)W);
      int pp = px + (ky - 1) * W + (kx - 1);
      fidx[ky * 3 + kx] = v ? (((pp >> 6) << 10) + (pp & 63)) : zb;
    }
}

// merged reg+cls 64->64 layer, K-split x4: block = one group x 4 K-quarters
// g 0-7 -> reg chain, 8-15 -> cls chain
__global__ __launch_bounds__(256) void k_conv3m(const float4* __restrict__ Fr, const float4* __restrict__ Fc,
                        float4* __restrict__ Or, float4* __restrict__ Oc,
                        const float* __restrict__ RWr, const float* __restrict__ RWc,
                        const float* __restrict__ br, const float* __restrict__ bc) {
  __shared__ float part[3][8][64];
  int S = blockIdx.x * 64;
  int l, off, W, sh; level_of(S, l, off, W, sh);
  int lane = threadIdx.x & 63;
  int kh = __builtin_amdgcn_readfirstlane(threadIdx.x >> 6);  // K-quarter 0..3
  int g = blockIdx.y;   // 0..15
  const float4* X; float4* O; const float* RW; const float* bias; int ocb;
  if (g < 8) { X = Fr; O = Or; RW = RWr; bias = br; ocb = g * 8; }
  else       { X = Fc; O = Oc; RW = RWc; bias = bc; ocb = (g - 8) * 8; }
  int px = S + lane;
  int fidx[9];
  tap_idx(px, off, W, sh, fidx);
  float acc[8];
#pragma unroll
  for (int o = 0; o < 8; ++o) acc[o] = 0.f;
  int c4base = kh * 4;
  const float4* W4 = (const float4*)RW + c4base;
#pragma unroll
  for (int t = 0; t < 9; ++t) {
    const float4* wb = W4 + (size_t)(t * 64 + ocb) * 16;
    int fi = fidx[t] + (c4base << 6);
#pragma unroll
    for (int c4 = 0; c4 < 4; ++c4) {
      float4 xv = X[fi + (c4 << 6)];
#pragma unroll
      for (int o = 0; o < 8; ++o) {
        float4 wv = wb[o * 16 + c4];
        acc[o] = fmaf(xv.x, wv.x, fmaf(xv.y, wv.y, fmaf(xv.z, wv.z, fmaf(xv.w, wv.w, acc[o]))));
      }
    }
  }
  if (kh) {
#pragma unroll
    for (int o = 0; o < 8; ++o) part[kh - 1][o][lane] = acc[o];
  }
  __syncthreads();
  if (kh || px >= P_TOT) return;
#pragma unroll
  for (int o = 0; o < 8; ++o)
    acc[o] += part[0][o][lane] + part[1][o][lane] + part[2][o][lane];
#pragma unroll
  for (int q = 0; q < 2; ++q) {
    float4 r;
    r.x = fmaxf(acc[q*4+0] + bias[ocb+q*4+0], 0.f);
    r.y = fmaxf(acc[q*4+1] + bias[ocb+q*4+1], 0.f);
    r.z = fmaxf(acc[q*4+2] + bias[ocb+q*4+2], 0.f);
    r.w = fmaxf(acc[q*4+3] + bias[ocb+q*4+3], 0.f);
    O[(blockIdx.x << 10) + (((ocb >> 2) + q) << 6) + lane] = r;
  }
}

// cls-out (90 groups) + reg-out (5 groups) conv, fused; K-split halves; 2 px/lane.
// Block = 2 groups x 2 K-halves; cls groups write per-anchor max keys to pamax,
// reg groups write REGb directly. key = mono32(logit)<<32 | (127-cls).
__global__ __launch_bounds__(256) void k_conv3c(const float4* __restrict__ Fc, const float4* __restrict__ Fr,
                        const float* __restrict__ RWc, const float* __restrict__ bc,
                        const float* __restrict__ RWr, const float* __restrict__ br,
                        u64* __restrict__ pamax, float* __restrict__ REGb) {
  __shared__ float part[2][8][128];
  int lane = threadIdx.x & 63;
  int wid = __builtin_amdgcn_readfirstlane(threadIdx.x >> 6);
  int gp = wid >> 1, kh = wid & 1;
  int g = blockIdx.y * 2 + gp;          // 0..95
  bool is_cls = g < 90;
  bool is_reg = (g >= 90) && (g < 95);
  int ocb, OCw; const float4* W4; const float4* F4;
  if (is_reg) { ocb = (g - 90) * 8; OCw = 36; W4 = (const float4*)RWr; F4 = Fr; }
  else        { ocb = is_cls ? g * 8 : 0; OCw = 720; W4 = (const float4*)RWc; F4 = Fc; }
  int S = blockIdx.x * 128;
  int px1 = S + lane;              // always < P_TOT (max 5439)
  int px2 = S + 64 + lane;
  bool ok2 = px2 < P_TOT;
  int l, off, W, sh;
  level_of(px1, l, off, W, sh);
  int f1[9];
  tap_idx(px1, off, W, sh, f1);
  int f2[9];
  if (ok2) {
    int l2, off2, W2, sh2;
    level_of(px2, l2, off2, W2, sh2);
    tap_idx(px2, off2, W2, sh2, f2);
  } else {
    int zb = (86 << 10) + lane;
#pragma unroll
    for (int t = 0; t < 9; ++t) f2[t] = zb;
  }
  float a1[8], a2[8];
#pragma unroll
  for (int o = 0; o < 8; ++o) { a1[o] = 0.f; a2[o] = 0.f; }
  int c4base = kh * 8;
  const float4* W4b = W4 + c4base;
#pragma unroll
  for (int t = 0; t < 9; ++t) {
    const float4* wb = W4b + (size_t)(t * OCw + ocb) * 16;
    int fi1 = f1[t] + (c4base << 6), fi2 = f2[t] + (c4base << 6);
#pragma unroll 4
    for (int c4 = 0; c4 < 8; ++c4) {
      float4 x1 = F4[fi1 + (c4 << 6)];
      float4 x2 = F4[fi2 + (c4 << 6)];
#pragma unroll
      for (int o = 0; o < 8; ++o) {
        float4 wv = wb[o * 16 + c4];
        a1[o] = fmaf(x1.x, wv.x, fmaf(x1.y, wv.y, fmaf(x1.z, wv.z, fmaf(x1.w, wv.w, a1[o]))));
        a2[o] = fmaf(x2.x, wv.x, fmaf(x2.y, wv.y, fmaf(x2.z, wv.z, fmaf(x2.w, wv.w, a2[o]))));
      }
    }
  }
  if (kh) {
#pragma unroll
    for (int o = 0; o < 8; ++o) {
      part[gp][o][lane] = a1[o];
      part[gp][o][64 + lane] = a2[o];
    }
  }
  __syncthreads();
  if (kh) return;
#pragma unroll
  for (int o = 0; o < 8; ++o) {
    a1[o] += part[gp][o][lane];
    a2[o] += part[gp][o][64 + lane];
  }
  if (is_cls) {
    int a0 = ocb / 80;
    int cls0 = ocb - a0 * 80;
    u64 k1 = 0ULL, k2 = 0ULL;
#pragma unroll
    for (int o = 0; o < 8; ++o) {
      float bi = bc[ocb + o];
      int cls = cls0 + o;
      u32 low = (u32)(127 - cls);
      float v1 = a1[o] + bi;
      u32 b1 = __float_as_uint(v1);
      b1 = (b1 & 0x80000000u) ? ~b1 : (b1 | 0x80000000u);
      u64 key1 = ((u64)b1 << 32) | low;
      k1 = k1 > key1 ? k1 : key1;
      float v2 = a2[o] + bi;
      u32 b2 = __float_as_uint(v2);
      b2 = (b2 & 0x80000000u) ? ~b2 : (b2 | 0x80000000u);
      u64 key2 = ((u64)b2 << 32) | low;
      k2 = k2 > key2 ? k2 : key2;
    }
    pamax[g * 5504 + px1] = k1;
    if (ok2) pamax[g * 5504 + px2] = k2;
  } else if (is_reg) {
    int nv = (g == 94) ? 4 : 8;
    for (int o = 0; o < nv; ++o) {
      int oc = ocb + o;
      float v1 = a1[o] + br[oc];
      REGb[((size_t)(px1 >> 6) * 9 + (oc >> 2)) * 256 + (px1 & 63) * 4 + (oc & 3)] = v1;
      if (ok2) {
        float v2 = a2[o] + br[oc];
        REGb[((size_t)(px2 >> 6) * 9 + (oc >> 2)) * 256 + (px2 & 63) * 4 + (oc & 3)] = v2;
      }
    }
  }
}

// ---------------- decode boxes + score/label from pamax ----------------
__global__ void k_decode_score(const float4* __restrict__ REG4, const u64* __restrict__ pamax,
                               float* __restrict__ score, int* __restrict__ label,
                               float* __restrict__ boxes, u32* __restrict__ ukey,
                               u32* __restrict__ hist1) {
  int aid = blockIdx.x * 256 + threadIdx.x;
  if (aid >= NANCH) return;
  int p = aid / 9;
  int a = aid - p * 9;
  int l, off, W, sh; level_of(p, l, off, W, sh);
  int loc = p - off, y = loc >> sh, x = loc & (W - 1);
  int s_idx = a % 3, r_idx = a / 3;
  double scale = (s_idx == 0) ? 1.0 : ((s_idx == 1) ? 1.2599210498948732 : 1.5874010519681994);
  double ratio = (r_idx == 0) ? 0.5 : ((r_idx == 1) ? 1.0 : 2.0);
  double strided = (double)(8 << l);
  double based = (double)(32 << l);
  double w0 = based * scale;
  double wA = sqrt(w0 * w0 / ratio);
  double hA = wA * ratio;
  double cxd = (x + 0.5) * strided;
  double cyd = (y + 0.5) * strided;
  float ax1 = (float)(cxd - wA / 2.0);
  float ay1 = (float)(cyd - hA / 2.0);
  float ax2 = (float)(cxd + wA / 2.0);
  float ay2 = (float)(cyd + hA / 2.0);
  float wa = ax2 - ax1, ha = ay2 - ay1;
  float cxa = ax1 + 0.5f * wa, cya = ay1 + 0.5f * ha;
  int blk = p >> 6, pxin = p & 63;
  float4 rq = REG4[blk * 576 + (a << 6) + pxin];
  float ncx = cxa + (rq.x * 0.1f) * wa;
  float ncy = cya + (rq.y * 0.1f) * ha;
  float nw = expf(rq.z * 0.2f) * wa;
  float nh = expf(rq.w * 0.2f) * ha;
  float bx1 = fmaxf(ncx - 0.5f * nw, 0.f);
  float by1 = fmaxf(ncy - 0.5f * nh, 0.f);
  float bx2 = fminf(ncx + 0.5f * nw, 512.f);
  float by2 = fminf(ncy + 0.5f * nh, 512.f);
  boxes[aid * 4 + 0] = bx1; boxes[aid * 4 + 1] = by1;
  boxes[aid * 4 + 2] = bx2; boxes[aid * 4 + 3] = by2;
  u64 key = 0ULL;
  const u64* pa = pamax + (size_t)(a * 10) * 5504 + p;
#pragma unroll
  for (int gi = 0; gi < 10; ++gi) {
    u64 k = pa[gi * 5504];
    key = key > k ? key : k;
  }
  u32 b = (u32)(key >> 32);
  b = (b & 0x80000000u) ? (b & 0x7FFFFFFFu) : ~b;
  float best = __uint_as_float(b);
  int bl = 127 - (int)(key & 0xFFFFFFFFu);
  float sc = 1.f / (1.f + expf(-best));
  score[aid] = sc; label[aid] = bl;
  u32 u = 0u;
  if (sc > 0.05f) u = __float_as_uint(sc) | 0x80000000u;
  ukey[aid] = u;
  if (u) atomicAdd(&hist1[u >> 16], 1u);
}

// ---------------- radix-select scans (parallel suffix scan) ----------------
__global__ __launch_bounds__(1024) void k_scanA(const u32* __restrict__ hist, u32* __restrict__ ctrl) {
  __shared__ u32 cs[1024];
  __shared__ u32 suf[1024];
  int t = threadIdx.x;
  u32 s = 0;
  int base = t * 64;
  for (int b = 0; b < 64; ++b) s += hist[base + b];
  cs[t] = s;
  suf[t] = s;
  __syncthreads();
  for (int d = 1; d < 1024; d <<= 1) {
    u32 v = (t + d < 1024) ? suf[t + d] : 0u;
    __syncthreads();
    suf[t] += v;
    __syncthreads();
  }
  u32 total = suf[0];
  if (total < (u32)KTOP) {
    if (t == 0) { ctrl[0] = 0x20000u; ctrl[1] = total; ctrl[2] = 1u; }
    return;
  }
  u32 excl = suf[t] - cs[t];
  if (excl < (u32)KTOP && excl + cs[t] >= (u32)KTOP) {
    u32 c2 = excl; int B1 = t * 64; u32 hB1 = 0;
    for (int b = t * 64 + 63; b >= t * 64; --b) {
      u32 h = hist[b];
      if (c2 + h >= (u32)KTOP) { B1 = b; hB1 = h; break; }
      c2 += h;
    }
    ctrl[0] = (u32)B1; ctrl[1] = c2;
    if (c2 + hB1 <= (u32)CAND_CAP) {   // whole bucket fits: skip pass 2
      ctrl[2] = (u32)B1 << 16;
      ctrl[5] = 1u;
    }
  }
}

__global__ void k_histB(const u32* __restrict__ ukey, u32* __restrict__ hist2,
                        const u32* __restrict__ ctrl) {
  if (ctrl[5]) return;
  int aid = blockIdx.x * 256 + threadIdx.x;
  if (aid >= NANCH) return;
  u32 u = ukey[aid];
  if (u && (u >> 16) == ctrl[0]) atomicAdd(&hist2[u & 0xFFFFu], 1u);
}

__global__ __launch_bounds__(1024) void k_scanB(const u32* __restrict__ hist, u32* __restrict__ ctrl) {
  if (ctrl[0] > 0xFFFFu || ctrl[5]) return;
  __shared__ u32 cs[1024];
  u32 s = 0;
  int base = threadIdx.x * 64;
  for (int b = 0; b < 64; ++b) s += hist[base + b];
  cs[threadIdx.x] = s;
  __syncthreads();
  if (threadIdx.x == 0) {
    u32 CA = ctrl[1];
    u32 cum = CA; int cc = -1;
    for (int tt = 1023; tt >= 0; --tt) {
      if (cum + cs[tt] >= (u32)KTOP) { cc = tt; break; }
      cum += cs[tt];
    }
    u32 B2 = 0;
    if (cc >= 0) {
      for (int b = cc * 64 + 63; b >= cc * 64; --b) {
        u32 h = hist[b];
        if (cum + h >= (u32)KTOP) { B2 = (u32)b; break; }
        cum += h;
      }
    }
    ctrl[2] = (ctrl[0] << 16) | B2;
  }
}

__global__ void k_compact(const u32* __restrict__ ukey, u64* __restrict__ cand,
                          u32* __restrict__ ctrl) {
  int aid = blockIdx.x * 256 + threadIdx.x;
  if (aid >= NANCH) return;
  u32 u = ukey[aid];
  u32 T = ctrl[2];
  if (u >= T && u != 0) {
    u32 pos = atomicAdd(&ctrl[3], 1u);
    if (pos < (u32)CAND_CAP)
      cand[pos] = (((u64)u) << 32) | (u32)(~(u32)aid);
  }
}

// ---------------- parallel rank-select top-1000 (exact, stable) ----------------
// key = score_bits<<32 | ~aid is unique; rank = #{j: key_j > key_i} gives exact
// jax.lax.top_k order (desc score, asc index tie-break).
__global__ __launch_bounds__(256) void k_rank(const u64* __restrict__ cand, u32* __restrict__ ctrl,
                                              const int* __restrict__ label,
                                              const float* __restrict__ boxes,
                                              float* __restrict__ tops, int* __restrict__ topl,
                                              float* __restrict__ topb) {
  __shared__ u64 key[CAND_CAP];
  int C = min((int)ctrl[3], CAND_CAP);
  for (int i = threadIdx.x; i < C; i += 256) key[i] = cand[i];
  __syncthreads();
  int i = blockIdx.x * 256 + threadIdx.x;
  if (i < C) {
    u64 ki = key[i];
    int rank = 0;
    for (int j = 0; j < C; ++j) rank += (key[j] > ki) ? 1 : 0;
    if (rank < KTOP) {
      u32 u = (u32)(ki >> 32);
      int aid = (int)(~((u32)ki));
      tops[rank] = __uint_as_float(u & 0x7FFFFFFFu);
      topl[rank] = label[aid];
      topb[rank * 4 + 0] = boxes[aid * 4 + 0];
      topb[rank * 4 + 1] = boxes[aid * 4 + 1];
      topb[rank * 4 + 2] = boxes[aid * 4 + 2];
      topb[rank * 4 + 3] = boxes[aid * 4 + 3];
    }
  }
  if (blockIdx.x == 0) {
    for (int r = threadIdx.x; r < KTOP; r += 256) {
      if (r >= C) {
        tops[r] = -1.f; topl[r] = -1;
        topb[r * 4 + 0] = 0.f; topb[r * 4 + 1] = 0.f;
        topb[r * 4 + 2] = 0.f; topb[r * 4 + 3] = 0.f;
      }
    }
    if (threadIdx.x == 0) ctrl[4] = (u32)min(C, KTOP);
  }
}

// ---------------- NMS ----------------
// IoU bitmask; sub-diagonal words (w < i/64) are zero-stored, not computed.
__global__ void k_iou(const float* __restrict__ topb, const u32* __restrict__ ctrl,
                      u64* __restrict__ mask) {
  int wid = threadIdx.x >> 6, lane = threadIdx.x & 63;
  int i = blockIdx.x * 4 + wid;
  int V = (int)ctrl[4];
  if (i >= V) return;
  float x1i = topb[i * 4], y1i = topb[i * 4 + 1], x2i = topb[i * 4 + 2], y2i = topb[i * 4 + 3];
  float ai = fmaxf(x2i - x1i, 0.f) * fmaxf(y2i - y1i, 0.f);
  int w0 = i >> 6;
  if (lane == 0)
    for (int w = 0; w < w0; ++w) mask[i * 16 + w] = 0ULL;
  for (int w = w0; w < 16; ++w) {
    int j = w * 64 + lane;
    bool bit = false;
    if (j < KTOP && j > i) {
      float x1j = topb[j * 4], y1j = topb[j * 4 + 1], x2j = topb[j * 4 + 2], y2j = topb[j * 4 + 3];
      float aj = fmaxf(x2j - x1j, 0.f) * fmaxf(y2j - y1j, 0.f);
      float iw = fmaxf(fminf(x2i, x2j) - fmaxf(x1i, x1j), 0.f);
      float ih = fmaxf(fminf(y2i, y2j) - fmaxf(y1i, y1j), 0.f);
      float inter = iw * ih;
      float iou = inter / (ai + aj - inter + 1e-8f);
      bit = iou > 0.5f;
    }
    u64 m = __ballot(bit);
    if (lane == 0) mask[i * 16 + w] = m;
  }
}

// NMS scan (wave 0) + final output (all 256 threads), fused
__global__ __launch_bounds__(256) void k_nmsfinal(const u64* __restrict__ mask,
                                                  const float* __restrict__ tops,
                                                  const int* __restrict__ topl,
                                                  const float* __restrict__ topb,
                                                  float* __restrict__ out) {
  __shared__ char kf[KTOP];
  int tid = threadIdx.x;
  if (tid < 64) {
    const int la = tid;
    const int rg = la >> 4;
    const int wg = la & 15;
    u64 remw = 0ULL;

#define LOADB(b, upd, intra, vsc) do {                                   \
    int rb = (b) * 64;                                                   \
    _Pragma("unroll")                                                    \
    for (int k = 0; k < 16; ++k)                                         \
      upd[k] = mask[(u32)(rb + rg + 4 * k) * 16u + (u32)wg];             \
    intra = mask[(u32)(rb + la) * 16u + (u32)(b)];                       \
    vsc = tops[rb + la];                                                 \
  } while (0)

#define PROC(b, upd, intra, vsc) do {                                    \
    u64 validmask = __ballot((vsc) > 0.05f);                             \
    u32 ilo = (u32)(intra);                                              \
    u32 ihi = (u32)((intra) >> 32);                                      \
    u64 supmask = ((u64)__builtin_amdgcn_readlane((int)(remw >> 32), (b)) << 32) | \
                  (u32)__builtin_amdgcn_readlane((int)(u32)remw, (b));   \
    u64 keptmask = 0ULL;                                                 \
    for (int i = 0; i < 64; ++i) {                                       \
      u32 rlo = (u32)__builtin_amdgcn_readlane((int)ilo, i);             \
      u32 rhi = (u32)__builtin_amdgcn_readlane((int)ihi, i);             \
      u64 take = (u64)0 - (((validmask >> i) & 1ULL) & (~(supmask >> i) & 1ULL)); \
      keptmask |= (1ULL << i) & take;                                    \
      supmask |= (((u64)rhi << 32) | rlo) & take;                       \
    }                                                                    \
    u64 kk = keptmask >> rg;                                             \
    u64 acc = 0ULL;                                                      \
    _Pragma("unroll")                                                    \
    for (int k = 0; k < 16; ++k)                                         \
      if ((kk >> (4 * k)) & 1ULL) acc |= upd[k];                         \
    acc |= __shfl_xor(acc, 16);                                          \
    acc |= __shfl_xor(acc, 32);                                          \
    remw |= acc;                                                         \
    int j = (b) * 64 + la;                                               \
    if (j < KTOP) kf[j] = (char)((keptmask >> la) & 1ULL);               \
  } while (0)

    u64 updA[16], updB[16];
    u64 intraA, intraB;
    float vscA, vscB;
    LOADB(0, updA, intraA, vscA);
    for (int bb = 0; bb < 16; bb += 2) {
      if (bb + 1 < 16) LOADB(bb + 1, updB, intraB, vscB);
      PROC(bb, updA, intraA, vscA);
      if (bb + 2 < 16) LOADB(bb + 2, updA, intraA, vscA);
      if (bb + 1 < 16) PROC(bb + 1, updB, intraB, vscB);
    }
#undef LOADB
#undef PROC
  }
  __syncthreads();
  for (int r = tid; r < KTOP; r += 256) {
    int k = kf[r];
    out[r] = k ? tops[r] : 0.f;
    out[KTOP + r] = k ? (float)topl[r] : -1.f;
    out[2 * KTOP + r * 4 + 0] = k ? topb[r * 4 + 0] : 0.f;
    out[2 * KTOP + r * 4 + 1] = k ? topb[r * 4 + 1] : 0.f;
    out[2 * KTOP + r * 4 + 2] = k ? topb[r * 4 + 2] : 0.f;
    out[2 * KTOP + r * 4 + 3] = k ? topb[r * 4 + 3] : 0.f;
  }
}

extern "C" void kernel_launch(void* const* d_in, const int* in_sizes, int n_in,
                              void* d_out, int out_size, void* d_ws, size_t ws_size,
                              hipStream_t stream) {
  const float* c3    = (const float*)d_in[0];
  const float* c4i   = (const float*)d_in[1];
  const float* c5    = (const float*)d_in[2];
  const float* w3    = (const float*)d_in[3];  const float* b3 = (const float*)d_in[4];
  const float* w4    = (const float*)d_in[5];  const float* b4 = (const float*)d_in[6];
  const float* w5    = (const float*)d_in[7];  const float* b5 = (const float*)d_in[8];
  const float* w6    = (const float*)d_in[9];  const float* b6 = (const float*)d_in[10];
  const float* w7    = (const float*)d_in[11]; const float* b7 = (const float*)d_in[12];
  const float* tdw   = (const float*)d_in[13]; const float* tdb  = (const float*)d_in[14];
  const float* tdg   = (const float*)d_in[15]; const float* tdbt = (const float*)d_in[16];
  const float* tdm   = (const float*)d_in[17]; const float* tdv  = (const float*)d_in[18];
  const float* ow    = (const float*)d_in[19]; const float* ob   = (const float*)d_in[20];
  const float* og    = (const float*)d_in[21]; const float* obt  = (const float*)d_in[22];
  const float* om    = (const float*)d_in[23]; const float* ov   = (const float*)d_in[24];
  const float* w1    = (const float*)d_in[25]; const float* w2   = (const float*)d_in[26];
  const float* clsw  = (const float*)d_in[27]; const float* clsb = (const float*)d_in[28];
  const float* clsow = (const float*)d_in[29]; const float* clsob= (const float*)d_in[30];
  const float* regw  = (const float*)d_in[31]; const float* regb = (const float*)d_in[32];
  const float* regow = (const float*)d_in[33]; const float* regob= (const float*)d_in[34];

  float* ws = (float*)d_ws;
  const size_t NF = 356352;                 // 87 blks * 4096 floats (blk 86 = zeros)
  float* A    = ws;
  float* Bb   = ws + NF;
  float* Cb   = ws + 2 * NF;
  float* Db   = ws + 3 * NF;
  float* RWc  = ws + 4 * NF;                // 110592
  float* RWco = RWc + 110592;               // 414720
  float* RWr  = RWco + 414720;              // 110592
  float* RWro = RWr + 110592;               // 20736 + 1024 pad
  float* REGb = RWro + 21760;               // 198144 (86*2304)
  u64*   pamax = (u64*)(REGb + 198144);     // 90*5504 u64 = 495360
  float* scoreb = (float*)(pamax + 495360); // 49104
  int*   labelb = (int*)(scoreb + 49104);   // 49104
  float* boxesb = (float*)(labelb + 49104); // 196416
  u32* hist1 = (u32*)(boxesb + 196416);     // 65536
  u32* hist2 = hist1 + 65536;               // 65536
  u32* ctrl  = hist2 + 65536;               // 64
  u64* cand  = (u64*)(ctrl + 64);           // 2048 u64
  float* tops = (float*)(cand + CAND_CAP);  // 1024
  int*   topl = (int*)(tops + 1024);        // 1024
  float* topb = (float*)(topl + 1024);      // 4096
  u64*   mask = (u64*)(topb + 4096);        // 16384 u64
  u32*   ukeyb = (u32*)(mask + 16384);      // 49104

  float4* A4 = (float4*)A; float4* B4 = (float4*)Bb;
  float4* C4 = (float4*)Cb; float4* D4 = (float4*)Db;
  float4* REG4 = (float4*)REGb;

  // prep: repack all head weights + zero hist/ctrl/zero-blocks/RWro-pad
  k_prep<<<dim3(3146), 256, 0, stream>>>(clsw, regw, clsow, regow, RWc, RWr, RWco, RWro,
                                         hist1, A, Bb, Cb, Db);

  // FPN inputs (batch 0 only) -> blocked layout, into A
  k_fpn_in<<<dim3(448), 256, 0, stream>>>(c3, w3, b3, c4i, w4, b4, c5, w5, b5, w6, b6, A, A4);
  k_conv_p7<<<dim3(64), 64, 0, stream>>>(w7, b7, A);

  // BiFPN x2 (read/write disjoint per kernel; K-split x4)
  k_td_t<<<dim3(86, 8), 256, 0, stream>>>(A4, B4, tdw, tdb, tdg, tdbt, tdm, tdv, w1, 0);
  k_out_t<<<dim3(86, 8), 256, 0, stream>>>(A4, B4, C4, ow, ob, og, obt, om, ov, w2, 0);
  k_td_t<<<dim3(86, 8), 256, 0, stream>>>(C4, B4, tdw, tdb, tdg, tdbt, tdm, tdv, w1, 1);
  k_out_t<<<dim3(86, 8), 256, 0, stream>>>(C4, B4, A4, ow, ob, og, obt, om, ov, w2, 1);

  // heads: merged reg+cls 64->64 layers (K-split x4), 4-buffer rotation
  k_conv3m<<<dim3(86, 16), 256, 0, stream>>>(A4, A4, C4, D4, RWr, RWc, regb, clsb);
  k_conv3m<<<dim3(86, 16), 256, 0, stream>>>(C4, D4, B4, A4, RWr + 36864, RWc + 36864, regb + 64, clsb + 64);
  k_conv3m<<<dim3(86, 16), 256, 0, stream>>>(B4, A4, C4, D4, RWr + 73728, RWc + 73728, regb + 128, clsb + 128);
  // reg final features in Cb, cls final features in Db; fused cls-out + reg-out
  k_conv3c<<<dim3(43, 48), 256, 0, stream>>>(D4, C4, RWco, clsob, RWro, regob, pamax, REGb);

  // decode + score + top-k + NMS
  k_decode_score<<<dim3(192), 256, 0, stream>>>(REG4, pamax, scoreb, labelb, boxesb, ukeyb, hist1);
  k_scanA<<<dim3(1), 1024, 0, stream>>>(hist1, ctrl);
  k_histB<<<dim3(192), 256, 0, stream>>>(ukeyb, hist2, ctrl);
  k_scanB<<<dim3(1), 1024, 0, stream>>>(hist2, ctrl);
  k_compact<<<dim3(192), 256, 0, stream>>>(ukeyb, cand, ctrl);
  k_rank<<<dim3(CAND_CAP / 256), 256, 0, stream>>>(cand, ctrl, labelb, boxesb, tops, topl, topb);
  k_iou<<<dim3(250), 256, 0, stream>>>(topb, ctrl, mask);
  k_nmsfinal<<<dim3(1), 256, 0, stream>>>(mask, tops, topl, topb, (float*)d_out);
}